// Round 8
// baseline (220.386 us; speedup 1.0000x reference)
//
#include <hip/hip_runtime.h>

// ---------------------------------------------------------------------------
// AttentionHead: B=4, C=256, N=4096, QK=64. Column-softmax attention.
// R20 = R19 (frag-major coalesced layouts, the 218.5us best) + k_attn LDS-op
// + barrier reduction:
//  - Swapped S MFMA: s = MFMA16(fk, aq) -- A/B frag lane-maps identical so
//    same registers; output flips to col=i,row=j so each lane holds 4
//    consecutive j for one i-row -> P written as 4x ds_write_b64 (ushort4)
//    instead of 16 scalar u16 (write ops 256->64/block-iter). Bit-identical
//    math (same products, same f32 acc order).
//  - P double-buffered -> ONE barrier/iter (WAR safe: reads of buf X at t
//    end before barrier t+1; writes to X resume after). S(t+1) overlaps PV(t).
//  - K fragments for t+1 prefetched before the barrier.
//  - rs loaded as one float4 per lane (j varies within lane now).
// R19 counters: k_attn 74us, Mfma 24%, LDS pipe ~5.5K cyc/iter (dominant:
// 256 b128 reads + 256 scalar writes + 1K conflict cyc), 2 barriers/iter.
// Other kernels byte-identical to R19.
// ---------------------------------------------------------------------------

typedef unsigned short u16;
typedef __attribute__((ext_vector_type(8))) unsigned short ushort8;
typedef __attribute__((ext_vector_type(4))) unsigned short ushort4v;
typedef __attribute__((ext_vector_type(8))) __bf16 bf16x8;
typedef __attribute__((ext_vector_type(4))) float f32x4;

#define MFMA16(a, b, c) __builtin_amdgcn_mfma_f32_16x16x32_bf16((a), (b), (c), 0, 0, 0)

__device__ __forceinline__ u16 f2bf(float f) {
  unsigned int u = __builtin_bit_cast(unsigned int, f);
  u += 0x7FFFu + ((u >> 16) & 1u);  // round-to-nearest-even
  return (u16)(u >> 16);
}

__device__ __forceinline__ bf16x8 ld8(const u16* p) {
  return __builtin_bit_cast(bf16x8, *reinterpret_cast<const ushort8*>(p));
}

__device__ __forceinline__ f32x4 fz4() {
  f32x4 z = {0.f, 0.f, 0.f, 0.f};
  return z;
}

// Fragment-major addressing (u16 units), per batch:
//  Qf/Kf: [istrip(256)][dc(2)][lane(64)][8]   -> ((istrip*2+dc)<<9) + lane*8
//  Vf   : [cstrip(16)][jchunk(128)][lane(64)][8] -> ((cstrip*128+jc)<<9)+lane*8
// lane = idx15 + 16*g holds tensor[idx = strip*16 + idx15][k = kchunk*8 + e].

// ---- convert all weight matrices fp32 -> bf16 (one launch) ----------------
__global__ __launch_bounds__(256) void k_convert(
    const float* __restrict__ wq, const float* __restrict__ wk,
    const float* __restrict__ wv, const float* __restrict__ w1,
    const float* __restrict__ w2, u16* __restrict__ dq, u16* __restrict__ dk,
    u16* __restrict__ dv, u16* __restrict__ d1, u16* __restrict__ d2) {
  int i = blockIdx.x * 256 + threadIdx.x;
  if (i < 16384)       dq[i]           = f2bf(wq[i]);
  else if (i < 32768)  dk[i - 16384]   = f2bf(wk[i - 16384]);
  else if (i < 98304)  dv[i - 32768]   = f2bf(wv[i - 32768]);
  else if (i < 163840) d1[i - 98304]   = f2bf(w1[i - 98304]);
  else                 d2[i - 163840]  = f2bf(w2[i - 163840]);
}

// ---- x [b][256][4096] fp32 -> xT [b][4096][256] bf16 (LDS-tiled) ----------
__global__ __launch_bounds__(256) void k_transpose(const float* __restrict__ x,
                                                   u16* __restrict__ xT) {
  __shared__ float t[64][65];
  int n0 = blockIdx.x * 64, c0 = blockIdx.y * 64, b = blockIdx.z;
  int tx = threadIdx.x & 63, ty = threadIdx.x >> 6;
  const float* xb = x + ((size_t)b * 256 + c0) * 4096 + n0;
#pragma unroll
  for (int i = 0; i < 64; i += 4) t[ty + i][tx] = xb[(size_t)(ty + i) * 4096 + tx];
  __syncthreads();
  u16* xo = xT + ((size_t)b * 4096 + n0) * 256 + c0;
#pragma unroll
  for (int i = 0; i < 64; i += 4) xo[(size_t)(ty + i) * 256 + tx] = f2bf(t[tx][ty + i]);
}

// ---- fused QKV projection: 32-pos tiles, grid 512 linear (b = id&3) -------
// Epilogue writes Q/K/V in fragment-major order (see map above).
__global__ __launch_bounds__(256) void k_proj(
    const u16* __restrict__ xT, const u16* __restrict__ wq,
    const u16* __restrict__ wk, const u16* __restrict__ wv,
    const float* __restrict__ bQ, const float* __restrict__ bK,
    const float* __restrict__ bV, const float* __restrict__ PE,
    u16* __restrict__ Qt, u16* __restrict__ Kt, u16* __restrict__ Vc) {
  int b = blockIdx.x & 3, n0 = (blockIdx.x >> 2) * 32;
  int lane = threadIdx.x & 63, wid = threadIdx.x >> 6;
  int l15 = lane & 15, g = lane >> 4;
  const u16* xrow = xT + ((size_t)b * 4096 + n0) * 256;

  f32x4 aq[2], ak[2], av[4][2];
#pragma unroll
  for (int m = 0; m < 2; ++m) { aq[m] = fz4(); ak[m] = fz4(); }
#pragma unroll
  for (int m = 0; m < 4; ++m)
#pragma unroll
    for (int n = 0; n < 2; ++n) av[m][n] = fz4();

  for (int kk = 0; kk < 8; ++kk) {
    int ko = kk * 32 + g * 8;
    bf16x8 xa[2];
#pragma unroll
    for (int m = 0; m < 2; ++m) xa[m] = ld8(xrow + (16 * m + l15) * 256 + ko);
    bf16x8 fq = ld8(wq + (16 * wid + l15) * 256 + ko);
    bf16x8 fk = ld8(wk + (16 * wid + l15) * 256 + ko);
#pragma unroll
    for (int m = 0; m < 2; ++m) {
      aq[m] = MFMA16(xa[m], fq, aq[m]);
      ak[m] = MFMA16(xa[m], fk, ak[m]);
    }
    bf16x8 fv[4];
#pragma unroll
    for (int m = 0; m < 4; ++m) fv[m] = ld8(wv + (64 * wid + 16 * m + l15) * 256 + ko);
#pragma unroll
    for (int m = 0; m < 4; ++m)
#pragma unroll
      for (int n = 0; n < 2; ++n) av[m][n] = MFMA16(fv[m], xa[n], av[m][n]);
  }

  // Q/K fragment writes: o = 16*wid+l15 (col), pos = n0+16m+4g+r (row)
  int o = 16 * wid + l15;
  int dc = wid >> 1;                      // o>>5
  int gp = (16 * (wid & 1) + l15) >> 3;   // (o&31)>>3
  int eo = l15 & 7;                       // o&7
  u16* qf = Qt + (size_t)b * 262144;
  u16* kf = Kt + (size_t)b * 262144;
#pragma unroll
  for (int m = 0; m < 2; ++m) {
    int istrip = (n0 >> 4) + m;
#pragma unroll
    for (int r = 0; r < 4; ++r) {
      int pos = n0 + 16 * m + 4 * g + r;
      float pe = PE[o * 4096 + pos];
      size_t a = (size_t)(((istrip * 2 + dc) << 9) + ((4 * g + r) + 16 * gp) * 8 + eo);
      qf[a] = f2bf(aq[m][r] + bQ[o] + pe);
      kf[a] = f2bf(ak[m][r] + bK[o] + pe);
    }
  }
  // V fragment writes: c = 64wid+16m+4g+r (row idx), pos = n0+16n+l15 (col k)
  u16* vf = Vc + (size_t)b * 1048576;
  int jchunk = n0 >> 5;
#pragma unroll
  for (int m = 0; m < 4; ++m) {
    int cstrip = 4 * wid + m;
#pragma unroll
    for (int r = 0; r < 4; ++r) {
      int c15 = 4 * g + r;
      float bvv = bV[64 * wid + 16 * m + c15];
#pragma unroll
      for (int n = 0; n < 2; ++n) {
        size_t a = (size_t)(((cstrip * 128 + jchunk) << 9) +
                            (c15 + 16 * (2 * n + (l15 >> 3))) * 8 + (l15 & 7));
        vf[a] = f2bf(av[m][n][r] + bvv);
      }
    }
  }
}

// ---- pass 1: column sums, 512 thr, grid 256 linear (b = id&3) -------------
// Q/K loads coalesced fragment bursts (base + lane*8).
__global__ __launch_bounds__(512) void k_colsum(const u16* __restrict__ Qt,
                                                const u16* __restrict__ Kt,
                                                float* __restrict__ rs) {
  __shared__ float ps[8][16];
  int b = blockIdx.x & 3, j0 = (blockIdx.x >> 2) * 64;
  int lane = threadIdx.x & 63, wid = threadIdx.x >> 6;  // wid in [0,8)
  int l15 = lane & 15, g = lane >> 4;
  int w4 = wid & 3, ihalf = wid >> 2;
  const u16* qf = Qt + (size_t)b * 262144;
  const u16* kf = Kt + (size_t)b * 262144;
  int j = j0 + 16 * w4 + l15;
  int jstrip = (j0 >> 4) + w4;
  bf16x8 fk[2];
#pragma unroll
  for (int h = 0; h < 2; ++h)
    fk[h] = ld8(kf + ((jstrip * 2 + h) << 9) + lane * 8);
  float part = 0.f;
  for (int i0 = ihalf * 2048; i0 < ihalf * 2048 + 2048; i0 += 64) {
    f32x4 acc[4];
#pragma unroll
    for (int m = 0; m < 4; ++m) acc[m] = fz4();
#pragma unroll
    for (int m = 0; m < 4; ++m) {
      int ib = ((i0 >> 4) + m) * 2;
      acc[m] = MFMA16(ld8(qf + (ib << 9) + lane * 8), fk[0], acc[m]);
      acc[m] = MFMA16(ld8(qf + ((ib + 1) << 9) + lane * 8), fk[1], acc[m]);
    }
#pragma unroll
    for (int m = 0; m < 4; ++m)
#pragma unroll
      for (int r = 0; r < 4; ++r) part += __expf(acc[m][r] * 0.125f);
  }
  part += __shfl_xor(part, 16);
  part += __shfl_xor(part, 32);
  if (g == 0) ps[wid][l15] = part;
  __syncthreads();
  if (ihalf == 0 && g == 0)
    rs[b * 4096 + j] = 1.0f / (ps[w4][l15] + ps[w4 + 4][l15]);
}

// ---- pass 2: attention, 1024 thr, grid 256 linear (b = id&3, XCD-pin) -----
// Swapped S (col=i,row=j) -> P written as 4x ds_write_b64/wave; P dbuf ->
// 1 barrier/iter; K(t+1) prefetched before barrier. PV 32i x 32c unchanged.
__global__ __launch_bounds__(1024) void k_attn(
    const u16* __restrict__ Qt, const u16* __restrict__ Kt,
    const u16* __restrict__ Vc, const float* __restrict__ rs,
    u16* __restrict__ attT) {
  __shared__ u16 P[2][64][264];  // dbuf; row 528 B (33x16B)
  int b = blockIdx.x & 3, i0 = (blockIdx.x >> 2) * 64;
  int lane = threadIdx.x & 63, wid = threadIdx.x >> 6;  // wid in [0,16)
  int l15 = lane & 15, g = lane >> 4;
  int ih = wid >> 3, cw = wid & 7;  // PV tile: i-half, 32-c strip
  const u16* qf = Qt + (size_t)b * 262144;
  const u16* kf = Kt + (size_t)b * 262144;
  const u16* vf = Vc + (size_t)b * 1048576;
  const float* rsb = rs + b * 4096;

  bf16x8 aq[4][2];  // block's Q rows (istrips i0/16 .. +3), all j
#pragma unroll
  for (int m = 0; m < 4; ++m)
#pragma unroll
    for (int h = 0; h < 2; ++h)
      aq[m][h] = ld8(qf + ((((i0 >> 4) + m) * 2 + h) << 9) + lane * 8);

  f32x4 oacc[2][2];  // [m][cs]: i = i0+32ih+16m+4g+r, c = 32cw+16cs+l15
#pragma unroll
  for (int m = 0; m < 2; ++m)
#pragma unroll
    for (int cs = 0; cs < 2; ++cs) oacc[m][cs] = fz4();

  const u16* kl = kf + lane * 8;
  bf16x8 fk0 = ld8(kl + ((wid * 2 + 0) << 9));
  bf16x8 fk1 = ld8(kl + ((wid * 2 + 1) << 9));

  int buf = 0;
  for (int j0 = 0; j0 < 4096; j0 += 256) {
    // S (swapped): lane holds S^T[j = j0+16wid+4g+r][i = i0+16m+l15]
    f32x4 rsc = *reinterpret_cast<const f32x4*>(rsb + j0 + 16 * wid + 4 * g);
    f32x4 s[4];
#pragma unroll
    for (int m = 0; m < 4; ++m) {
      s[m] = fz4();
      s[m] = MFMA16(fk0, aq[m][0], s[m]);
      s[m] = MFMA16(fk1, aq[m][1], s[m]);
    }
#pragma unroll
    for (int m = 0; m < 4; ++m) {
      ushort4v pk;
#pragma unroll
      for (int r = 0; r < 4; ++r)
        pk[r] = f2bf(__expf(s[m][r] * 0.125f) * rsc[r]);
      *reinterpret_cast<ushort4v*>(&P[buf][16 * m + l15][16 * wid + 4 * g]) = pk;
    }
    // prefetch next K fragments (in flight across barrier + PV)
    if (j0 < 3840) {
      int jstrip = ((j0 + 256) >> 4) + wid;
      fk0 = ld8(kl + ((jstrip * 2 + 0) << 9));
      fk1 = ld8(kl + ((jstrip * 2 + 1) << 9));
    }
    __syncthreads();
    // PV: A = P rows (ih half, 2 m), B = V fragment bursts (strips 2cw,2cw+1)
#pragma unroll
    for (int h = 0; h < 8; ++h) {
      bf16x8 ap[2];
#pragma unroll
      for (int m = 0; m < 2; ++m)
        ap[m] = ld8(&P[buf][32 * ih + 16 * m + l15][h * 32 + 8 * g]);
      bf16x8 fv[2];
#pragma unroll
      for (int cs = 0; cs < 2; ++cs)
        fv[cs] = ld8(vf + (((2 * cw + cs) * 128 + (j0 >> 5) + h) << 9) + lane * 8);
#pragma unroll
      for (int m = 0; m < 2; ++m)
#pragma unroll
        for (int cs = 0; cs < 2; ++cs)
          oacc[m][cs] = MFMA16(ap[m], fv[cs], oacc[m][cs]);
    }
    buf ^= 1;  // WAR safe: reads of this buf ended before the barrier above
  }
#pragma unroll
  for (int m = 0; m < 2; ++m)
#pragma unroll
    for (int cs = 0; cs < 2; ++cs) {
      int c = 32 * cw + 16 * cs + l15;
#pragma unroll
      for (int r = 0; r < 4; ++r) {
        int pos = i0 + 32 * ih + 16 * m + 4 * g + r;
        attT[((size_t)b * 4096 + pos) * 256 + c] = f2bf(oacc[m][cs][r]);
      }
    }
}

// ---- fused MLP, 512 thr, grid 256 linear (b = id&3) -----------------------
__global__ __launch_bounds__(512) void k_mlp(
    const u16* __restrict__ attT, const u16* __restrict__ w1,
    const float* __restrict__ b1, const u16* __restrict__ w2,
    const float* __restrict__ b2, const float* __restrict__ x,
    float* __restrict__ out) {
  __shared__ u16 hdnS[64][264];
  int b = blockIdx.x & 3, n0 = (blockIdx.x >> 2) * 64;
  int lane = threadIdx.x & 63, wid = threadIdx.x >> 6;  // wid in [0,8)
  int l15 = lane & 15, g = lane >> 4;
  const u16* arow = attT + ((size_t)b * 4096 + n0) * 256;

  // stage 1: hdn = mish(att @ W1^T + b1) -> LDS; wave strip = 32 h-channels
  {
    f32x4 acc[4][2];
#pragma unroll
    for (int m = 0; m < 4; ++m)
#pragma unroll
      for (int n = 0; n < 2; ++n) acc[m][n] = fz4();
    for (int kk = 0; kk < 8; ++kk) {
      int ko = kk * 32 + 8 * g;
      bf16x8 am[4], bn[2];
#pragma unroll
      for (int m = 0; m < 4; ++m) am[m] = ld8(arow + (16 * m + l15) * 256 + ko);
#pragma unroll
      for (int n = 0; n < 2; ++n) bn[n] = ld8(w1 + (32 * wid + 16 * n + l15) * 256 + ko);
#pragma unroll
      for (int m = 0; m < 4; ++m)
#pragma unroll
        for (int n = 0; n < 2; ++n) acc[m][n] = MFMA16(am[m], bn[n], acc[m][n]);
    }
#pragma unroll
    for (int m = 0; m < 4; ++m)
#pragma unroll
      for (int n = 0; n < 2; ++n) {
        int hh = 32 * wid + 16 * n + l15;
        float bb = b1[hh];
#pragma unroll
        for (int r = 0; r < 4; ++r) {
          float v = acc[m][n][r] + bb;
          float sp = (v > 15.f) ? v : __logf(1.f + __expf(v));
          float e2 = __expf(-2.f * sp);
          float th = (1.f - e2) / (1.f + e2);
          hdnS[16 * m + 4 * g + r][hh] = f2bf(v * th);
        }
      }
  }
  __syncthreads();

  // stage 2: out = hdn @ W2^T + b2 + x; wave strip = 32 o-channels
  {
    f32x4 acc[2][4];
#pragma unroll
    for (int m = 0; m < 2; ++m)
#pragma unroll
      for (int n = 0; n < 4; ++n) acc[m][n] = fz4();
    for (int kk = 0; kk < 8; ++kk) {
      int ko = kk * 32 + 8 * g;
      bf16x8 am[2], bn[4];
#pragma unroll
      for (int m = 0; m < 2; ++m) am[m] = ld8(w2 + (32 * wid + 16 * m + l15) * 256 + ko);
#pragma unroll
      for (int n = 0; n < 4; ++n) bn[n] = ld8(&hdnS[16 * n + l15][ko]);
#pragma unroll
      for (int m = 0; m < 2; ++m)
#pragma unroll
        for (int n = 0; n < 4; ++n) acc[m][n] = MFMA16(am[m], bn[n], acc[m][n]);
    }
#pragma unroll
    for (int m = 0; m < 2; ++m)
#pragma unroll
      for (int r = 0; r < 4; ++r) {
        int o = 32 * wid + 16 * m + 4 * g + r;
        float bias = b2[o];
#pragma unroll
        for (int n = 0; n < 4; ++n) {
          int pos = n0 + 16 * n + l15;
          size_t idx = ((size_t)b * 256 + o) * 4096 + pos;
          out[idx] = acc[m][n][r] + bias + x[idx];
        }
      }
  }
}

// ---- workspace layout (bytes) ---------------------------------------------
// attT aliases xT (xT dead after k_proj; attT written by k_attn, read k_mlp).
#define WS_XT 0u          //  8,388,608  xT  [4][4096][256] bf16  (= attT)
#define WS_ATT 0u         //  8,388,608  attT[4][4096][256] bf16  (= xT)
#define WS_QT 8388608u    //  2,097,152  Qf  [4][256][2][64][8] bf16 (frag)
#define WS_KT 10485760u   //  2,097,152  Kf  [4][256][2][64][8] bf16 (frag)
#define WS_VC 12582912u   //  8,388,608  Vf  [4][16][128][64][8] bf16 (frag)
#define WS_RS 20971520u   //     65,536  rs  [4][4096]      fp32
#define WS_WQ 21037056u   //     32,768
#define WS_WK 21069824u   //     32,768
#define WS_WV 21102592u   //    131,072
#define WS_W1 21233664u   //    131,072
#define WS_W2 21364736u   //    131,072   (end: 21,495,808 < 29,884,416)

extern "C" void kernel_launch(void* const* d_in, const int* in_sizes, int n_in,
                              void* d_out, int out_size, void* d_ws, size_t ws_size,
                              hipStream_t stream) {
  (void)in_sizes; (void)n_in; (void)out_size; (void)ws_size;
  const float* x  = (const float*)d_in[0];
  const float* WQ = (const float*)d_in[1];
  const float* bQ = (const float*)d_in[2];
  const float* WK = (const float*)d_in[3];
  const float* bK = (const float*)d_in[4];
  const float* WV = (const float*)d_in[5];
  const float* bV = (const float*)d_in[6];
  const float* PE = (const float*)d_in[7];
  const float* W1 = (const float*)d_in[8];
  const float* b1 = (const float*)d_in[9];
  const float* W2 = (const float*)d_in[10];
  const float* b2 = (const float*)d_in[11];
  float* out = (float*)d_out;
  char* ws = (char*)d_ws;

  u16* xT   = (u16*)(ws + WS_XT);
  u16* Qt   = (u16*)(ws + WS_QT);
  u16* Kt   = (u16*)(ws + WS_KT);
  u16* Vc   = (u16*)(ws + WS_VC);
  u16* attT = (u16*)(ws + WS_ATT);
  float* rs = (float*)(ws + WS_RS);
  u16* wqB  = (u16*)(ws + WS_WQ);
  u16* wkB  = (u16*)(ws + WS_WK);
  u16* wvB  = (u16*)(ws + WS_WV);
  u16* w1B  = (u16*)(ws + WS_W1);
  u16* w2B  = (u16*)(ws + WS_W2);

  k_convert<<<896, 256, 0, stream>>>(WQ, WK, WV, W1, W2, wqB, wkB, wvB, w1B, w2B);
  k_transpose<<<dim3(64, 4, 4), 256, 0, stream>>>(x, xT);
  k_proj<<<512, 256, 0, stream>>>(xT, wqB, wkB, wvB, bQ, bK, bV, PE, Qt, Kt, Vc);
  k_colsum<<<256, 512, 0, stream>>>(Qt, Kt, rs);
  k_attn<<<256, 1024, 0, stream>>>(Qt, Kt, Vc, rs, attT);
  k_mlp<<<256, 512, 0, stream>>>(attT, w1B, b1, w2B, b2, x, out);
}

// Round 9
// 214.034 us; speedup vs baseline: 1.0297x; 1.0297x over previous
//
#include <hip/hip_runtime.h>

// ---------------------------------------------------------------------------
// AttentionHead: B=4, C=256, N=4096, QK=64. Column-softmax attention.
// R21 = R20 (frag-major layouts + swapped-S b64 P-writes + dbuf 1-barrier)
// + wave-role STAGGER in k_attn, + VGPR cap relax:
//  - Between barriers a wave does [PV(t); S(t+1)] (independent: PV reads
//    buf, S writes buf^1; barrier covers both hazard directions). Order is
//    free per wave -> odd waves run S-FIRST, even waves PV-FIRST. At any
//    instant ~half the waves feed LDS/VMEM (PV) and half feed MFMA/VALU (S),
//    overlapping pipes that R20 ran in lockstep phases (pipe arithmetic:
//    sum-serial 13-14K cyc/iter ~= measured 10.85K; max-overlap ~5K).
//  - __launch_bounds__(1024,4): VGPR cap 52->128 (1 block/CU = 4 waves/SIMD,
//    128 free) so the scheduler can hoist more PV loads.
// Other kernels byte-identical to R20/R19.
// ---------------------------------------------------------------------------

typedef unsigned short u16;
typedef __attribute__((ext_vector_type(8))) unsigned short ushort8;
typedef __attribute__((ext_vector_type(4))) unsigned short ushort4v;
typedef __attribute__((ext_vector_type(8))) __bf16 bf16x8;
typedef __attribute__((ext_vector_type(4))) float f32x4;

#define MFMA16(a, b, c) __builtin_amdgcn_mfma_f32_16x16x32_bf16((a), (b), (c), 0, 0, 0)

__device__ __forceinline__ u16 f2bf(float f) {
  unsigned int u = __builtin_bit_cast(unsigned int, f);
  u += 0x7FFFu + ((u >> 16) & 1u);  // round-to-nearest-even
  return (u16)(u >> 16);
}

__device__ __forceinline__ bf16x8 ld8(const u16* p) {
  return __builtin_bit_cast(bf16x8, *reinterpret_cast<const ushort8*>(p));
}

__device__ __forceinline__ f32x4 fz4() {
  f32x4 z = {0.f, 0.f, 0.f, 0.f};
  return z;
}

// Fragment-major addressing (u16 units), per batch:
//  Qf/Kf: [istrip(256)][dc(2)][lane(64)][8]   -> ((istrip*2+dc)<<9) + lane*8
//  Vf   : [cstrip(16)][jchunk(128)][lane(64)][8] -> ((cstrip*128+jc)<<9)+lane*8
// lane = idx15 + 16*g holds tensor[idx = strip*16 + idx15][k = kchunk*8 + e].

// ---- convert all weight matrices fp32 -> bf16 (one launch) ----------------
__global__ __launch_bounds__(256) void k_convert(
    const float* __restrict__ wq, const float* __restrict__ wk,
    const float* __restrict__ wv, const float* __restrict__ w1,
    const float* __restrict__ w2, u16* __restrict__ dq, u16* __restrict__ dk,
    u16* __restrict__ dv, u16* __restrict__ d1, u16* __restrict__ d2) {
  int i = blockIdx.x * 256 + threadIdx.x;
  if (i < 16384)       dq[i]           = f2bf(wq[i]);
  else if (i < 32768)  dk[i - 16384]   = f2bf(wk[i - 16384]);
  else if (i < 98304)  dv[i - 32768]   = f2bf(wv[i - 32768]);
  else if (i < 163840) d1[i - 98304]   = f2bf(w1[i - 98304]);
  else                 d2[i - 163840]  = f2bf(w2[i - 163840]);
}

// ---- x [b][256][4096] fp32 -> xT [b][4096][256] bf16 (LDS-tiled) ----------
__global__ __launch_bounds__(256) void k_transpose(const float* __restrict__ x,
                                                   u16* __restrict__ xT) {
  __shared__ float t[64][65];
  int n0 = blockIdx.x * 64, c0 = blockIdx.y * 64, b = blockIdx.z;
  int tx = threadIdx.x & 63, ty = threadIdx.x >> 6;
  const float* xb = x + ((size_t)b * 256 + c0) * 4096 + n0;
#pragma unroll
  for (int i = 0; i < 64; i += 4) t[ty + i][tx] = xb[(size_t)(ty + i) * 4096 + tx];
  __syncthreads();
  u16* xo = xT + ((size_t)b * 4096 + n0) * 256 + c0;
#pragma unroll
  for (int i = 0; i < 64; i += 4) xo[(size_t)(ty + i) * 256 + tx] = f2bf(t[tx][ty + i]);
}

// ---- fused QKV projection: 32-pos tiles, grid 512 linear (b = id&3) -------
// Epilogue writes Q/K/V in fragment-major order (see map above).
__global__ __launch_bounds__(256) void k_proj(
    const u16* __restrict__ xT, const u16* __restrict__ wq,
    const u16* __restrict__ wk, const u16* __restrict__ wv,
    const float* __restrict__ bQ, const float* __restrict__ bK,
    const float* __restrict__ bV, const float* __restrict__ PE,
    u16* __restrict__ Qt, u16* __restrict__ Kt, u16* __restrict__ Vc) {
  int b = blockIdx.x & 3, n0 = (blockIdx.x >> 2) * 32;
  int lane = threadIdx.x & 63, wid = threadIdx.x >> 6;
  int l15 = lane & 15, g = lane >> 4;
  const u16* xrow = xT + ((size_t)b * 4096 + n0) * 256;

  f32x4 aq[2], ak[2], av[4][2];
#pragma unroll
  for (int m = 0; m < 2; ++m) { aq[m] = fz4(); ak[m] = fz4(); }
#pragma unroll
  for (int m = 0; m < 4; ++m)
#pragma unroll
    for (int n = 0; n < 2; ++n) av[m][n] = fz4();

  for (int kk = 0; kk < 8; ++kk) {
    int ko = kk * 32 + g * 8;
    bf16x8 xa[2];
#pragma unroll
    for (int m = 0; m < 2; ++m) xa[m] = ld8(xrow + (16 * m + l15) * 256 + ko);
    bf16x8 fq = ld8(wq + (16 * wid + l15) * 256 + ko);
    bf16x8 fk = ld8(wk + (16 * wid + l15) * 256 + ko);
#pragma unroll
    for (int m = 0; m < 2; ++m) {
      aq[m] = MFMA16(xa[m], fq, aq[m]);
      ak[m] = MFMA16(xa[m], fk, ak[m]);
    }
    bf16x8 fv[4];
#pragma unroll
    for (int m = 0; m < 4; ++m) fv[m] = ld8(wv + (64 * wid + 16 * m + l15) * 256 + ko);
#pragma unroll
    for (int m = 0; m < 4; ++m)
#pragma unroll
      for (int n = 0; n < 2; ++n) av[m][n] = MFMA16(fv[m], xa[n], av[m][n]);
  }

  // Q/K fragment writes: o = 16*wid+l15 (col), pos = n0+16m+4g+r (row)
  int o = 16 * wid + l15;
  int dc = wid >> 1;                      // o>>5
  int gp = (16 * (wid & 1) + l15) >> 3;   // (o&31)>>3
  int eo = l15 & 7;                       // o&7
  u16* qf = Qt + (size_t)b * 262144;
  u16* kf = Kt + (size_t)b * 262144;
#pragma unroll
  for (int m = 0; m < 2; ++m) {
    int istrip = (n0 >> 4) + m;
#pragma unroll
    for (int r = 0; r < 4; ++r) {
      int pos = n0 + 16 * m + 4 * g + r;
      float pe = PE[o * 4096 + pos];
      size_t a = (size_t)(((istrip * 2 + dc) << 9) + ((4 * g + r) + 16 * gp) * 8 + eo);
      qf[a] = f2bf(aq[m][r] + bQ[o] + pe);
      kf[a] = f2bf(ak[m][r] + bK[o] + pe);
    }
  }
  // V fragment writes: c = 64wid+16m+4g+r (row idx), pos = n0+16n+l15 (col k)
  u16* vf = Vc + (size_t)b * 1048576;
  int jchunk = n0 >> 5;
#pragma unroll
  for (int m = 0; m < 4; ++m) {
    int cstrip = 4 * wid + m;
#pragma unroll
    for (int r = 0; r < 4; ++r) {
      int c15 = 4 * g + r;
      float bvv = bV[64 * wid + 16 * m + c15];
#pragma unroll
      for (int n = 0; n < 2; ++n) {
        size_t a = (size_t)(((cstrip * 128 + jchunk) << 9) +
                            (c15 + 16 * (2 * n + (l15 >> 3))) * 8 + (l15 & 7));
        vf[a] = f2bf(av[m][n][r] + bvv);
      }
    }
  }
}

// ---- pass 1: column sums, 512 thr, grid 256 linear (b = id&3) -------------
// Q/K loads coalesced fragment bursts (base + lane*8).
__global__ __launch_bounds__(512) void k_colsum(const u16* __restrict__ Qt,
                                                const u16* __restrict__ Kt,
                                                float* __restrict__ rs) {
  __shared__ float ps[8][16];
  int b = blockIdx.x & 3, j0 = (blockIdx.x >> 2) * 64;
  int lane = threadIdx.x & 63, wid = threadIdx.x >> 6;  // wid in [0,8)
  int l15 = lane & 15, g = lane >> 4;
  int w4 = wid & 3, ihalf = wid >> 2;
  const u16* qf = Qt + (size_t)b * 262144;
  const u16* kf = Kt + (size_t)b * 262144;
  int j = j0 + 16 * w4 + l15;
  int jstrip = (j0 >> 4) + w4;
  bf16x8 fk[2];
#pragma unroll
  for (int h = 0; h < 2; ++h)
    fk[h] = ld8(kf + ((jstrip * 2 + h) << 9) + lane * 8);
  float part = 0.f;
  for (int i0 = ihalf * 2048; i0 < ihalf * 2048 + 2048; i0 += 64) {
    f32x4 acc[4];
#pragma unroll
    for (int m = 0; m < 4; ++m) acc[m] = fz4();
#pragma unroll
    for (int m = 0; m < 4; ++m) {
      int ib = ((i0 >> 4) + m) * 2;
      acc[m] = MFMA16(ld8(qf + (ib << 9) + lane * 8), fk[0], acc[m]);
      acc[m] = MFMA16(ld8(qf + ((ib + 1) << 9) + lane * 8), fk[1], acc[m]);
    }
#pragma unroll
    for (int m = 0; m < 4; ++m)
#pragma unroll
      for (int r = 0; r < 4; ++r) part += __expf(acc[m][r] * 0.125f);
  }
  part += __shfl_xor(part, 16);
  part += __shfl_xor(part, 32);
  if (g == 0) ps[wid][l15] = part;
  __syncthreads();
  if (ihalf == 0 && g == 0)
    rs[b * 4096 + j] = 1.0f / (ps[w4][l15] + ps[w4 + 4][l15]);
}

// ---- pass 2: attention, 1024 thr, grid 256 linear (b = id&3, XCD-pin) -----
// Staggered roles: odd waves S(t+1)-then-PV(t), even waves PV(t)-then-S(t+1).
// Safe: PV(t) reads buf, S(t+1) writes buf^1; the span-opening barrier covers
// both directions (all reads of buf^1 ended pre-barrier).
__global__ __launch_bounds__(1024, 4) void k_attn(
    const u16* __restrict__ Qt, const u16* __restrict__ Kt,
    const u16* __restrict__ Vc, const float* __restrict__ rs,
    u16* __restrict__ attT) {
  __shared__ u16 P[2][64][264];  // dbuf; row 528 B (33x16B)
  int b = blockIdx.x & 3, i0 = (blockIdx.x >> 2) * 64;
  int lane = threadIdx.x & 63, wid = threadIdx.x >> 6;  // wid in [0,16)
  int l15 = lane & 15, g = lane >> 4;
  int ih = wid >> 3, cw = wid & 7;  // PV tile: i-half, 32-c strip
  const u16* qf = Qt + (size_t)b * 262144;
  const u16* kf = Kt + (size_t)b * 262144;
  const u16* vf = Vc + (size_t)b * 1048576;
  const float* rsb = rs + b * 4096;

  bf16x8 aq[4][2];  // block's Q rows (istrips i0/16 .. +3), all j
#pragma unroll
  for (int m = 0; m < 4; ++m)
#pragma unroll
    for (int h = 0; h < 2; ++h)
      aq[m][h] = ld8(qf + ((((i0 >> 4) + m) * 2 + h) << 9) + lane * 8);

  f32x4 oacc[2][2];  // [m][cs]: i = i0+32ih+16m+4g+r, c = 32cw+16cs+l15
#pragma unroll
  for (int m = 0; m < 2; ++m)
#pragma unroll
    for (int cs = 0; cs < 2; ++cs) oacc[m][cs] = fz4();

  const u16* kl = kf + lane * 8;
  bf16x8 fk0 = ld8(kl + ((wid * 2 + 0) << 9));
  bf16x8 fk1 = ld8(kl + ((wid * 2 + 1) << 9));

  // S for target j0 into P[sbuf]; consumes fk(j0), advances fk to j0+256.
  auto S_phase = [&](int j0, int sbuf) {
    f32x4 rsc = *reinterpret_cast<const f32x4*>(rsb + j0 + 16 * wid + 4 * g);
    f32x4 s[4];
#pragma unroll
    for (int m = 0; m < 4; ++m) {
      s[m] = fz4();
      s[m] = MFMA16(fk0, aq[m][0], s[m]);
      s[m] = MFMA16(fk1, aq[m][1], s[m]);
    }
#pragma unroll
    for (int m = 0; m < 4; ++m) {
      ushort4v pk;
#pragma unroll
      for (int r = 0; r < 4; ++r)
        pk[r] = f2bf(__expf(s[m][r] * 0.125f) * rsc[r]);
      *reinterpret_cast<ushort4v*>(&P[sbuf][16 * m + l15][16 * wid + 4 * g]) = pk;
    }
    if (j0 < 3840) {  // prefetch K(j0+256)
      int jstrip = ((j0 + 256) >> 4) + wid;
      fk0 = ld8(kl + ((jstrip * 2 + 0) << 9));
      fk1 = ld8(kl + ((jstrip * 2 + 1) << 9));
    }
  };
  // PV for j0 from P[pbuf].
  auto PV_phase = [&](int j0, int pbuf) {
#pragma unroll
    for (int h = 0; h < 8; ++h) {
      bf16x8 ap[2];
#pragma unroll
      for (int m = 0; m < 2; ++m)
        ap[m] = ld8(&P[pbuf][32 * ih + 16 * m + l15][h * 32 + 8 * g]);
      bf16x8 fv[2];
#pragma unroll
      for (int cs = 0; cs < 2; ++cs)
        fv[cs] = ld8(vf + (((2 * cw + cs) * 128 + (j0 >> 5) + h) << 9) + lane * 8);
#pragma unroll
      for (int m = 0; m < 2; ++m)
#pragma unroll
        for (int cs = 0; cs < 2; ++cs)
          oacc[m][cs] = MFMA16(ap[m], fv[cs], oacc[m][cs]);
    }
  };

  S_phase(0, 0);  // prologue fills buf 0
  int buf = 0;
  for (int t = 0; t < 16; ++t) {
    __syncthreads();
    int j0 = t * 256;
    if (wid & 1) {  // S-first waves
      if (t < 15) S_phase(j0 + 256, buf ^ 1);
      PV_phase(j0, buf);
    } else {        // PV-first waves
      PV_phase(j0, buf);
      if (t < 15) S_phase(j0 + 256, buf ^ 1);
    }
    buf ^= 1;
  }

#pragma unroll
  for (int m = 0; m < 2; ++m)
#pragma unroll
    for (int cs = 0; cs < 2; ++cs) {
      int c = 32 * cw + 16 * cs + l15;
#pragma unroll
      for (int r = 0; r < 4; ++r) {
        int pos = i0 + 32 * ih + 16 * m + 4 * g + r;
        attT[((size_t)b * 4096 + pos) * 256 + c] = f2bf(oacc[m][cs][r]);
      }
    }
}

// ---- fused MLP, 512 thr, grid 256 linear (b = id&3) -----------------------
__global__ __launch_bounds__(512) void k_mlp(
    const u16* __restrict__ attT, const u16* __restrict__ w1,
    const float* __restrict__ b1, const u16* __restrict__ w2,
    const float* __restrict__ b2, const float* __restrict__ x,
    float* __restrict__ out) {
  __shared__ u16 hdnS[64][264];
  int b = blockIdx.x & 3, n0 = (blockIdx.x >> 2) * 64;
  int lane = threadIdx.x & 63, wid = threadIdx.x >> 6;  // wid in [0,8)
  int l15 = lane & 15, g = lane >> 4;
  const u16* arow = attT + ((size_t)b * 4096 + n0) * 256;

  // stage 1: hdn = mish(att @ W1^T + b1) -> LDS; wave strip = 32 h-channels
  {
    f32x4 acc[4][2];
#pragma unroll
    for (int m = 0; m < 4; ++m)
#pragma unroll
      for (int n = 0; n < 2; ++n) acc[m][n] = fz4();
    for (int kk = 0; kk < 8; ++kk) {
      int ko = kk * 32 + 8 * g;
      bf16x8 am[4], bn[2];
#pragma unroll
      for (int m = 0; m < 4; ++m) am[m] = ld8(arow + (16 * m + l15) * 256 + ko);
#pragma unroll
      for (int n = 0; n < 2; ++n) bn[n] = ld8(w1 + (32 * wid + 16 * n + l15) * 256 + ko);
#pragma unroll
      for (int m = 0; m < 4; ++m)
#pragma unroll
        for (int n = 0; n < 2; ++n) acc[m][n] = MFMA16(am[m], bn[n], acc[m][n]);
    }
#pragma unroll
    for (int m = 0; m < 4; ++m)
#pragma unroll
      for (int n = 0; n < 2; ++n) {
        int hh = 32 * wid + 16 * n + l15;
        float bb = b1[hh];
#pragma unroll
        for (int r = 0; r < 4; ++r) {
          float v = acc[m][n][r] + bb;
          float sp = (v > 15.f) ? v : __logf(1.f + __expf(v));
          float e2 = __expf(-2.f * sp);
          float th = (1.f - e2) / (1.f + e2);
          hdnS[16 * m + 4 * g + r][hh] = f2bf(v * th);
        }
      }
  }
  __syncthreads();

  // stage 2: out = hdn @ W2^T + b2 + x; wave strip = 32 o-channels
  {
    f32x4 acc[2][4];
#pragma unroll
    for (int m = 0; m < 2; ++m)
#pragma unroll
      for (int n = 0; n < 4; ++n) acc[m][n] = fz4();
    for (int kk = 0; kk < 8; ++kk) {
      int ko = kk * 32 + 8 * g;
      bf16x8 am[2], bn[4];
#pragma unroll
      for (int m = 0; m < 2; ++m) am[m] = ld8(w2 + (32 * wid + 16 * m + l15) * 256 + ko);
#pragma unroll
      for (int n = 0; n < 4; ++n) bn[n] = ld8(&hdnS[16 * n + l15][ko]);
#pragma unroll
      for (int m = 0; m < 2; ++m)
#pragma unroll
        for (int n = 0; n < 4; ++n) acc[m][n] = MFMA16(am[m], bn[n], acc[m][n]);
    }
#pragma unroll
    for (int m = 0; m < 2; ++m)
#pragma unroll
      for (int r = 0; r < 4; ++r) {
        int o = 32 * wid + 16 * m + 4 * g + r;
        float bias = b2[o];
#pragma unroll
        for (int n = 0; n < 4; ++n) {
          int pos = n0 + 16 * n + l15;
          size_t idx = ((size_t)b * 256 + o) * 4096 + pos;
          out[idx] = acc[m][n][r] + bias + x[idx];
        }
      }
  }
}

// ---- workspace layout (bytes) ---------------------------------------------
// attT aliases xT (xT dead after k_proj; attT written by k_attn, read k_mlp).
#define WS_XT 0u          //  8,388,608  xT  [4][4096][256] bf16  (= attT)
#define WS_ATT 0u         //  8,388,608  attT[4][4096][256] bf16  (= xT)
#define WS_QT 8388608u    //  2,097,152  Qf  [4][256][2][64][8] bf16 (frag)
#define WS_KT 10485760u   //  2,097,152  Kf  [4][256][2][64][8] bf16 (frag)
#define WS_VC 12582912u   //  8,388,608  Vf  [4][16][128][64][8] bf16 (frag)
#define WS_RS 20971520u   //     65,536  rs  [4][4096]      fp32
#define WS_WQ 21037056u   //     32,768
#define WS_WK 21069824u   //     32,768
#define WS_WV 21102592u   //    131,072
#define WS_W1 21233664u   //    131,072
#define WS_W2 21364736u   //    131,072   (end: 21,495,808 < 29,884,416)

extern "C" void kernel_launch(void* const* d_in, const int* in_sizes, int n_in,
                              void* d_out, int out_size, void* d_ws, size_t ws_size,
                              hipStream_t stream) {
  (void)in_sizes; (void)n_in; (void)out_size; (void)ws_size;
  const float* x  = (const float*)d_in[0];
  const float* WQ = (const float*)d_in[1];
  const float* bQ = (const float*)d_in[2];
  const float* WK = (const float*)d_in[3];
  const float* bK = (const float*)d_in[4];
  const float* WV = (const float*)d_in[5];
  const float* bV = (const float*)d_in[6];
  const float* PE = (const float*)d_in[7];
  const float* W1 = (const float*)d_in[8];
  const float* b1 = (const float*)d_in[9];
  const float* W2 = (const float*)d_in[10];
  const float* b2 = (const float*)d_in[11];
  float* out = (float*)d_out;
  char* ws = (char*)d_ws;

  u16* xT   = (u16*)(ws + WS_XT);
  u16* Qt   = (u16*)(ws + WS_QT);
  u16* Kt   = (u16*)(ws + WS_KT);
  u16* Vc   = (u16*)(ws + WS_VC);
  u16* attT = (u16*)(ws + WS_ATT);
  float* rs = (float*)(ws + WS_RS);
  u16* wqB  = (u16*)(ws + WS_WQ);
  u16* wkB  = (u16*)(ws + WS_WK);
  u16* wvB  = (u16*)(ws + WS_WV);
  u16* w1B  = (u16*)(ws + WS_W1);
  u16* w2B  = (u16*)(ws + WS_W2);

  k_convert<<<896, 256, 0, stream>>>(WQ, WK, WV, W1, W2, wqB, wkB, wvB, w1B, w2B);
  k_transpose<<<dim3(64, 4, 4), 256, 0, stream>>>(x, xT);
  k_proj<<<512, 256, 0, stream>>>(xT, wqB, wkB, wvB, bQ, bK, bV, PE, Qt, Kt, Vc);
  k_colsum<<<256, 512, 0, stream>>>(Qt, Kt, rs);
  k_attn<<<256, 1024, 0, stream>>>(Qt, Kt, Vc, rs, attT);
  k_mlp<<<256, 512, 0, stream>>>(attT, w1B, b1, w2B, b2, x, out);
}

// Round 10
// 212.964 us; speedup vs baseline: 1.0349x; 1.0050x over previous
//
#include <hip/hip_runtime.h>

// ---------------------------------------------------------------------------
// AttentionHead: B=4, C=256, N=4096, QK=64. Column-softmax attention.
// R22 = R21 (frag-major + swapped-S + dbuf + stagger) + three measured cuts:
//  - T14 V-hoist: fv[2][4] (h=0..3) issued at span top, consumed after the
//    S-phase (~1-2K cyc cover). R21's VGPR=56 showed the compiler never
//    hoisted V itself -> VMEM latency sat on the PV critical path.
//  - VALU cut: rs folded into V (k_colsum scales Vf in place, frag-major;
//    variant verified end-to-end in R14) and P packed via v_cvt_pk_bf16_f32
//    (8 cvt_pk replace ~64 bit-ops of manual f2bf) -> ~1K cyc/iter VALU.
//  - T5 setprio(1) around PV (stagger provides the role-split regime).
// Other kernels byte-identical to R21 except k_colsum epilogue.
// ---------------------------------------------------------------------------

typedef unsigned short u16;
typedef __attribute__((ext_vector_type(8))) unsigned short ushort8;
typedef __attribute__((ext_vector_type(2))) unsigned int uint2v;
typedef __attribute__((ext_vector_type(8))) __bf16 bf16x8;
typedef __attribute__((ext_vector_type(4))) float f32x4;

#define MFMA16(a, b, c) __builtin_amdgcn_mfma_f32_16x16x32_bf16((a), (b), (c), 0, 0, 0)

__device__ __forceinline__ u16 f2bf(float f) {
  unsigned int u = __builtin_bit_cast(unsigned int, f);
  u += 0x7FFFu + ((u >> 16) & 1u);  // round-to-nearest-even
  return (u16)(u >> 16);
}

__device__ __forceinline__ float bf2f(u16 v) {
  return __builtin_bit_cast(float, (unsigned int)v << 16);
}

__device__ __forceinline__ unsigned int cvtpk(float lo, float hi) {
  unsigned int r;
  asm("v_cvt_pk_bf16_f32 %0, %1, %2" : "=v"(r) : "v"(lo), "v"(hi));
  return r;
}

__device__ __forceinline__ bf16x8 ld8(const u16* p) {
  return __builtin_bit_cast(bf16x8, *reinterpret_cast<const ushort8*>(p));
}

__device__ __forceinline__ f32x4 fz4() {
  f32x4 z = {0.f, 0.f, 0.f, 0.f};
  return z;
}

// Fragment-major addressing (u16 units), per batch:
//  Qf/Kf: [istrip(256)][dc(2)][lane(64)][8]   -> ((istrip*2+dc)<<9) + lane*8
//  Vf   : [cstrip(16)][jchunk(128)][lane(64)][8] -> ((cstrip*128+jc)<<9)+lane*8
// lane = idx15 + 16*g holds tensor[idx = strip*16 + idx15][k = kchunk*8 + e].

// ---- convert all weight matrices fp32 -> bf16 (one launch) ----------------
__global__ __launch_bounds__(256) void k_convert(
    const float* __restrict__ wq, const float* __restrict__ wk,
    const float* __restrict__ wv, const float* __restrict__ w1,
    const float* __restrict__ w2, u16* __restrict__ dq, u16* __restrict__ dk,
    u16* __restrict__ dv, u16* __restrict__ d1, u16* __restrict__ d2) {
  int i = blockIdx.x * 256 + threadIdx.x;
  if (i < 16384)       dq[i]           = f2bf(wq[i]);
  else if (i < 32768)  dk[i - 16384]   = f2bf(wk[i - 16384]);
  else if (i < 98304)  dv[i - 32768]   = f2bf(wv[i - 32768]);
  else if (i < 163840) d1[i - 98304]   = f2bf(w1[i - 98304]);
  else                 d2[i - 163840]  = f2bf(w2[i - 163840]);
}

// ---- x [b][256][4096] fp32 -> xT [b][4096][256] bf16 (LDS-tiled) ----------
__global__ __launch_bounds__(256) void k_transpose(const float* __restrict__ x,
                                                   u16* __restrict__ xT) {
  __shared__ float t[64][65];
  int n0 = blockIdx.x * 64, c0 = blockIdx.y * 64, b = blockIdx.z;
  int tx = threadIdx.x & 63, ty = threadIdx.x >> 6;
  const float* xb = x + ((size_t)b * 256 + c0) * 4096 + n0;
#pragma unroll
  for (int i = 0; i < 64; i += 4) t[ty + i][tx] = xb[(size_t)(ty + i) * 4096 + tx];
  __syncthreads();
  u16* xo = xT + ((size_t)b * 4096 + n0) * 256 + c0;
#pragma unroll
  for (int i = 0; i < 64; i += 4) xo[(size_t)(ty + i) * 256 + tx] = f2bf(t[tx][ty + i]);
}

// ---- fused QKV projection: 32-pos tiles, grid 512 linear (b = id&3) -------
// Epilogue writes Q/K/V in fragment-major order (see map above).
__global__ __launch_bounds__(256) void k_proj(
    const u16* __restrict__ xT, const u16* __restrict__ wq,
    const u16* __restrict__ wk, const u16* __restrict__ wv,
    const float* __restrict__ bQ, const float* __restrict__ bK,
    const float* __restrict__ bV, const float* __restrict__ PE,
    u16* __restrict__ Qt, u16* __restrict__ Kt, u16* __restrict__ Vc) {
  int b = blockIdx.x & 3, n0 = (blockIdx.x >> 2) * 32;
  int lane = threadIdx.x & 63, wid = threadIdx.x >> 6;
  int l15 = lane & 15, g = lane >> 4;
  const u16* xrow = xT + ((size_t)b * 4096 + n0) * 256;

  f32x4 aq[2], ak[2], av[4][2];
#pragma unroll
  for (int m = 0; m < 2; ++m) { aq[m] = fz4(); ak[m] = fz4(); }
#pragma unroll
  for (int m = 0; m < 4; ++m)
#pragma unroll
    for (int n = 0; n < 2; ++n) av[m][n] = fz4();

  for (int kk = 0; kk < 8; ++kk) {
    int ko = kk * 32 + g * 8;
    bf16x8 xa[2];
#pragma unroll
    for (int m = 0; m < 2; ++m) xa[m] = ld8(xrow + (16 * m + l15) * 256 + ko);
    bf16x8 fq = ld8(wq + (16 * wid + l15) * 256 + ko);
    bf16x8 fk = ld8(wk + (16 * wid + l15) * 256 + ko);
#pragma unroll
    for (int m = 0; m < 2; ++m) {
      aq[m] = MFMA16(xa[m], fq, aq[m]);
      ak[m] = MFMA16(xa[m], fk, ak[m]);
    }
    bf16x8 fv[4];
#pragma unroll
    for (int m = 0; m < 4; ++m) fv[m] = ld8(wv + (64 * wid + 16 * m + l15) * 256 + ko);
#pragma unroll
    for (int m = 0; m < 4; ++m)
#pragma unroll
      for (int n = 0; n < 2; ++n) av[m][n] = MFMA16(fv[m], xa[n], av[m][n]);
  }

  // Q/K fragment writes: o = 16*wid+l15 (col), pos = n0+16m+4g+r (row)
  int o = 16 * wid + l15;
  int dc = wid >> 1;                      // o>>5
  int gp = (16 * (wid & 1) + l15) >> 3;   // (o&31)>>3
  int eo = l15 & 7;                       // o&7
  u16* qf = Qt + (size_t)b * 262144;
  u16* kf = Kt + (size_t)b * 262144;
#pragma unroll
  for (int m = 0; m < 2; ++m) {
    int istrip = (n0 >> 4) + m;
#pragma unroll
    for (int r = 0; r < 4; ++r) {
      int pos = n0 + 16 * m + 4 * g + r;
      float pe = PE[o * 4096 + pos];
      size_t a = (size_t)(((istrip * 2 + dc) << 9) + ((4 * g + r) + 16 * gp) * 8 + eo);
      qf[a] = f2bf(aq[m][r] + bQ[o] + pe);
      kf[a] = f2bf(ak[m][r] + bK[o] + pe);
    }
  }
  // V fragment writes: c = 64wid+16m+4g+r (row idx), pos = n0+16n+l15 (col k)
  u16* vf = Vc + (size_t)b * 1048576;
  int jchunk = n0 >> 5;
#pragma unroll
  for (int m = 0; m < 4; ++m) {
    int cstrip = 4 * wid + m;
#pragma unroll
    for (int r = 0; r < 4; ++r) {
      int c15 = 4 * g + r;
      float bvv = bV[64 * wid + 16 * m + c15];
#pragma unroll
      for (int n = 0; n < 2; ++n) {
        size_t a = (size_t)(((cstrip * 128 + jchunk) << 9) +
                            (c15 + 16 * (2 * n + (l15 >> 3))) * 8 + (l15 & 7));
        vf[a] = f2bf(av[m][n][r] + bvv);
      }
    }
  }
}

// ---- pass 1: column sums + fold 1/colsum into Vf, 512 thr, grid 256 -------
// Same S body as R21; epilogue scales Vf[:, j0..j0+63] in place (frag-major)
// so k_attn's P = exp(S/8) purely (R14-verified variant).
__global__ __launch_bounds__(512) void k_colsum(const u16* __restrict__ Qt,
                                                const u16* __restrict__ Kt,
                                                u16* __restrict__ Vc) {
  __shared__ float ps[8][16];
  __shared__ float rsf[64];
  int b = blockIdx.x & 3, j0 = (blockIdx.x >> 2) * 64;
  int lane = threadIdx.x & 63, wid = threadIdx.x >> 6;  // wid in [0,8)
  int l15 = lane & 15, g = lane >> 4;
  int w4 = wid & 3, ihalf = wid >> 2;
  const u16* qf = Qt + (size_t)b * 262144;
  const u16* kf = Kt + (size_t)b * 262144;
  int jstrip = (j0 >> 4) + w4;
  bf16x8 fk[2];
#pragma unroll
  for (int h = 0; h < 2; ++h)
    fk[h] = ld8(kf + ((jstrip * 2 + h) << 9) + lane * 8);
  float part = 0.f;
  for (int i0 = ihalf * 2048; i0 < ihalf * 2048 + 2048; i0 += 64) {
    f32x4 acc[4];
#pragma unroll
    for (int m = 0; m < 4; ++m) acc[m] = fz4();
#pragma unroll
    for (int m = 0; m < 4; ++m) {
      int ib = ((i0 >> 4) + m) * 2;
      acc[m] = MFMA16(ld8(qf + (ib << 9) + lane * 8), fk[0], acc[m]);
      acc[m] = MFMA16(ld8(qf + ((ib + 1) << 9) + lane * 8), fk[1], acc[m]);
    }
#pragma unroll
    for (int m = 0; m < 4; ++m)
#pragma unroll
      for (int r = 0; r < 4; ++r) part += __expf(acc[m][r] * 0.125f);
  }
  part += __shfl_xor(part, 16);
  part += __shfl_xor(part, 32);
  if (g == 0) ps[wid][l15] = part;
  __syncthreads();
  if (threadIdx.x < 64) {
    int jj = threadIdx.x;
    rsf[jj] = 1.0f / (ps[jj >> 4][jj & 15] + ps[(jj >> 4) + 4][jj & 15]);
  }
  __syncthreads();
  // scale Vf for j in [j0, j0+64), all 256 channels (2 threads / channel)
  {
    int c = threadIdx.x >> 1, half = threadIdx.x & 1;
    int cstrip = c >> 4, c15 = c & 15;
    u16* vb2 = Vc + (size_t)b * 1048576;
#pragma unroll
    for (int q = 0; q < 2; ++q) {
      int jo = half * 32 + q * 16;  // 2 ushort8 groups per q step
#pragma unroll
      for (int s = 0; s < 2; ++s) {
        int joo = jo + s * 8;                 // j offset within 64, /8 aligned
        int jc = (j0 + joo) >> 5;             // absolute jchunk
        int jg = (joo & 31) >> 3;             // lane group
        u16* p = vb2 + (((size_t)(cstrip * 128 + jc)) << 9) + (c15 + 16 * jg) * 8;
        ushort8 v = *reinterpret_cast<const ushort8*>(p);
        ushort8 ov;
#pragma unroll
        for (int e = 0; e < 8; ++e) ov[e] = f2bf(bf2f(v[e]) * rsf[joo + e]);
        *reinterpret_cast<ushort8*>(p) = ov;
      }
    }
  }
}

// ---- pass 2: attention, 1024 thr, grid 256 linear (b = id&3, XCD-pin) -----
// Stagger + dbuf + frag loads; V(h<4) hoisted to span top (T14); P packed
// via cvt_pk; rs pre-folded into Vf; setprio(1) around PV (T5).
__global__ __launch_bounds__(1024, 4) void k_attn(
    const u16* __restrict__ Qt, const u16* __restrict__ Kt,
    const u16* __restrict__ Vc, u16* __restrict__ attT) {
  __shared__ u16 P[2][64][264];  // dbuf; row 528 B (33x16B)
  int b = blockIdx.x & 3, i0 = (blockIdx.x >> 2) * 64;
  int lane = threadIdx.x & 63, wid = threadIdx.x >> 6;  // wid in [0,16)
  int l15 = lane & 15, g = lane >> 4;
  int ih = wid >> 3, cw = wid & 7;  // PV tile: i-half, 32-c strip
  const u16* qf = Qt + (size_t)b * 262144;
  const u16* kf = Kt + (size_t)b * 262144;
  const u16* vf = Vc + (size_t)b * 1048576;

  bf16x8 aq[4][2];  // block's Q rows (istrips i0/16 .. +3), all j
#pragma unroll
  for (int m = 0; m < 4; ++m)
#pragma unroll
    for (int h = 0; h < 2; ++h)
      aq[m][h] = ld8(qf + ((((i0 >> 4) + m) * 2 + h) << 9) + lane * 8);

  f32x4 oacc[2][2];  // [m][cs]: i = i0+32ih+16m+4g+r, c = 32cw+16cs+l15
#pragma unroll
  for (int m = 0; m < 2; ++m)
#pragma unroll
    for (int cs = 0; cs < 2; ++cs) oacc[m][cs] = fz4();

  const u16* kl = kf + lane * 8;
  bf16x8 fk0 = ld8(kl + ((wid * 2 + 0) << 9));
  bf16x8 fk1 = ld8(kl + ((wid * 2 + 1) << 9));

  // S for target j0 into P[sbuf]; consumes fk(j0), advances fk to j0+256.
  auto S_phase = [&](int j0, int sbuf) {
    f32x4 s[4];
#pragma unroll
    for (int m = 0; m < 4; ++m) {
      s[m] = fz4();
      s[m] = MFMA16(fk0, aq[m][0], s[m]);
      s[m] = MFMA16(fk1, aq[m][1], s[m]);
    }
#pragma unroll
    for (int m = 0; m < 4; ++m) {
      float e0 = __expf(s[m][0] * 0.125f);
      float e1 = __expf(s[m][1] * 0.125f);
      float e2 = __expf(s[m][2] * 0.125f);
      float e3 = __expf(s[m][3] * 0.125f);
      uint2v w = {cvtpk(e0, e1), cvtpk(e2, e3)};
      *reinterpret_cast<uint2v*>(&P[sbuf][16 * m + l15][16 * wid + 4 * g]) = w;
    }
    if (j0 < 3840) {  // prefetch K(j0+256)
      int jstrip = ((j0 + 256) >> 4) + wid;
      fk0 = ld8(kl + ((jstrip * 2 + 0) << 9));
      fk1 = ld8(kl + ((jstrip * 2 + 1) << 9));
    }
  };
  // PV for j0 from P[pbuf]; fvp holds hoisted V for h=0..3.
  auto PV_phase = [&](int j0, int pbuf, const bf16x8 (&fvp)[2][4]) {
    __builtin_amdgcn_s_setprio(1);
#pragma unroll
    for (int h = 0; h < 8; ++h) {
      bf16x8 ap[2];
#pragma unroll
      for (int m = 0; m < 2; ++m)
        ap[m] = ld8(&P[pbuf][32 * ih + 16 * m + l15][h * 32 + 8 * g]);
      bf16x8 f0, f1;
      if (h < 4) {
        f0 = fvp[0][h];
        f1 = fvp[1][h];
      } else {
        f0 = ld8(vf + (((2 * cw + 0) * 128 + (j0 >> 5) + h) << 9) + lane * 8);
        f1 = ld8(vf + (((2 * cw + 1) * 128 + (j0 >> 5) + h) << 9) + lane * 8);
      }
      oacc[0][0] = MFMA16(ap[0], f0, oacc[0][0]);
      oacc[0][1] = MFMA16(ap[0], f1, oacc[0][1]);
      oacc[1][0] = MFMA16(ap[1], f0, oacc[1][0]);
      oacc[1][1] = MFMA16(ap[1], f1, oacc[1][1]);
    }
    __builtin_amdgcn_s_setprio(0);
  };

  S_phase(0, 0);  // prologue fills buf 0
  int buf = 0;
  for (int t = 0; t < 16; ++t) {
    __syncthreads();
    int j0 = t * 256;
    // T14: issue first half of this span's V loads; consumed after S-phase
    bf16x8 fvp[2][4];
#pragma unroll
    for (int cs = 0; cs < 2; ++cs)
#pragma unroll
      for (int h = 0; h < 4; ++h)
        fvp[cs][h] = ld8(vf + (((2 * cw + cs) * 128 + (j0 >> 5) + h) << 9) + lane * 8);
    if (wid & 1) {  // S-first waves
      if (t < 15) S_phase(j0 + 256, buf ^ 1);
      PV_phase(j0, buf, fvp);
    } else {        // PV-first waves
      PV_phase(j0, buf, fvp);
      if (t < 15) S_phase(j0 + 256, buf ^ 1);
    }
    buf ^= 1;
  }

#pragma unroll
  for (int m = 0; m < 2; ++m)
#pragma unroll
    for (int cs = 0; cs < 2; ++cs) {
      int c = 32 * cw + 16 * cs + l15;
#pragma unroll
      for (int r = 0; r < 4; ++r) {
        int pos = i0 + 32 * ih + 16 * m + 4 * g + r;
        attT[((size_t)b * 4096 + pos) * 256 + c] = f2bf(oacc[m][cs][r]);
      }
    }
}

// ---- fused MLP, 512 thr, grid 256 linear (b = id&3) -----------------------
__global__ __launch_bounds__(512) void k_mlp(
    const u16* __restrict__ attT, const u16* __restrict__ w1,
    const float* __restrict__ b1, const u16* __restrict__ w2,
    const float* __restrict__ b2, const float* __restrict__ x,
    float* __restrict__ out) {
  __shared__ u16 hdnS[64][264];
  int b = blockIdx.x & 3, n0 = (blockIdx.x >> 2) * 64;
  int lane = threadIdx.x & 63, wid = threadIdx.x >> 6;  // wid in [0,8)
  int l15 = lane & 15, g = lane >> 4;
  const u16* arow = attT + ((size_t)b * 4096 + n0) * 256;

  // stage 1: hdn = mish(att @ W1^T + b1) -> LDS; wave strip = 32 h-channels
  {
    f32x4 acc[4][2];
#pragma unroll
    for (int m = 0; m < 4; ++m)
#pragma unroll
      for (int n = 0; n < 2; ++n) acc[m][n] = fz4();
    for (int kk = 0; kk < 8; ++kk) {
      int ko = kk * 32 + 8 * g;
      bf16x8 am[4], bn[2];
#pragma unroll
      for (int m = 0; m < 4; ++m) am[m] = ld8(arow + (16 * m + l15) * 256 + ko);
#pragma unroll
      for (int n = 0; n < 2; ++n) bn[n] = ld8(w1 + (32 * wid + 16 * n + l15) * 256 + ko);
#pragma unroll
      for (int m = 0; m < 4; ++m)
#pragma unroll
        for (int n = 0; n < 2; ++n) acc[m][n] = MFMA16(am[m], bn[n], acc[m][n]);
    }
#pragma unroll
    for (int m = 0; m < 4; ++m)
#pragma unroll
      for (int n = 0; n < 2; ++n) {
        int hh = 32 * wid + 16 * n + l15;
        float bb = b1[hh];
#pragma unroll
        for (int r = 0; r < 4; ++r) {
          float v = acc[m][n][r] + bb;
          float sp = (v > 15.f) ? v : __logf(1.f + __expf(v));
          float e2 = __expf(-2.f * sp);
          float th = (1.f - e2) / (1.f + e2);
          hdnS[16 * m + 4 * g + r][hh] = f2bf(v * th);
        }
      }
  }
  __syncthreads();

  // stage 2: out = hdn @ W2^T + b2 + x; wave strip = 32 o-channels
  {
    f32x4 acc[2][4];
#pragma unroll
    for (int m = 0; m < 2; ++m)
#pragma unroll
      for (int n = 0; n < 4; ++n) acc[m][n] = fz4();
    for (int kk = 0; kk < 8; ++kk) {
      int ko = kk * 32 + 8 * g;
      bf16x8 am[2], bn[4];
#pragma unroll
      for (int m = 0; m < 2; ++m) am[m] = ld8(w2 + (32 * wid + 16 * m + l15) * 256 + ko);
#pragma unroll
      for (int n = 0; n < 4; ++n) bn[n] = ld8(&hdnS[16 * n + l15][ko]);
#pragma unroll
      for (int m = 0; m < 2; ++m)
#pragma unroll
        for (int n = 0; n < 4; ++n) acc[m][n] = MFMA16(am[m], bn[n], acc[m][n]);
    }
#pragma unroll
    for (int m = 0; m < 2; ++m)
#pragma unroll
      for (int r = 0; r < 4; ++r) {
        int o = 32 * wid + 16 * m + 4 * g + r;
        float bias = b2[o];
#pragma unroll
        for (int n = 0; n < 4; ++n) {
          int pos = n0 + 16 * n + l15;
          size_t idx = ((size_t)b * 256 + o) * 4096 + pos;
          out[idx] = acc[m][n][r] + bias + x[idx];
        }
      }
  }
}

// ---- workspace layout (bytes) ---------------------------------------------
// attT aliases xT (xT dead after k_proj; attT written by k_attn, read k_mlp).
#define WS_XT 0u          //  8,388,608  xT  [4][4096][256] bf16  (= attT)
#define WS_ATT 0u         //  8,388,608  attT[4][4096][256] bf16  (= xT)
#define WS_QT 8388608u    //  2,097,152  Qf  [4][256][2][64][8] bf16 (frag)
#define WS_KT 10485760u   //  2,097,152  Kf  [4][256][2][64][8] bf16 (frag)
#define WS_VC 12582912u   //  8,388,608  Vf  [4][16][128][64][8] bf16 (frag)
#define WS_RS 20971520u   //     65,536  (unused since R22)
#define WS_WQ 21037056u   //     32,768
#define WS_WK 21069824u   //     32,768
#define WS_WV 21102592u   //    131,072
#define WS_W1 21233664u   //    131,072
#define WS_W2 21364736u   //    131,072   (end: 21,495,808 < 29,884,416)

extern "C" void kernel_launch(void* const* d_in, const int* in_sizes, int n_in,
                              void* d_out, int out_size, void* d_ws, size_t ws_size,
                              hipStream_t stream) {
  (void)in_sizes; (void)n_in; (void)out_size; (void)ws_size;
  const float* x  = (const float*)d_in[0];
  const float* WQ = (const float*)d_in[1];
  const float* bQ = (const float*)d_in[2];
  const float* WK = (const float*)d_in[3];
  const float* bK = (const float*)d_in[4];
  const float* WV = (const float*)d_in[5];
  const float* bV = (const float*)d_in[6];
  const float* PE = (const float*)d_in[7];
  const float* W1 = (const float*)d_in[8];
  const float* b1 = (const float*)d_in[9];
  const float* W2 = (const float*)d_in[10];
  const float* b2 = (const float*)d_in[11];
  float* out = (float*)d_out;
  char* ws = (char*)d_ws;

  u16* xT   = (u16*)(ws + WS_XT);
  u16* Qt   = (u16*)(ws + WS_QT);
  u16* Kt   = (u16*)(ws + WS_KT);
  u16* Vc   = (u16*)(ws + WS_VC);
  u16* attT = (u16*)(ws + WS_ATT);
  u16* wqB  = (u16*)(ws + WS_WQ);
  u16* wkB  = (u16*)(ws + WS_WK);
  u16* wvB  = (u16*)(ws + WS_WV);
  u16* w1B  = (u16*)(ws + WS_W1);
  u16* w2B  = (u16*)(ws + WS_W2);

  k_convert<<<896, 256, 0, stream>>>(WQ, WK, WV, W1, W2, wqB, wkB, wvB, w1B, w2B);
  k_transpose<<<dim3(64, 4, 4), 256, 0, stream>>>(x, xT);
  k_proj<<<512, 256, 0, stream>>>(xT, wqB, wkB, wvB, bQ, bK, bV, PE, Qt, Kt, Vc);
  k_colsum<<<256, 512, 0, stream>>>(Qt, Kt, Vc);
  k_attn<<<256, 1024, 0, stream>>>(Qt, Kt, Vc, attT);
  k_mlp<<<256, 512, 0, stream>>>(attT, w1B, b1, w2B, b2, x, out);
}

// Round 11
// 210.247 us; speedup vs baseline: 1.0482x; 1.0129x over previous
//
#include <hip/hip_runtime.h>

// ---------------------------------------------------------------------------
// AttentionHead: B=4, C=256, N=4096, QK=64. Column-softmax attention.
// R23 = R22 + fragment-major layouts EVERYWHERE (R19's proven 2.1x mechanism
// applied to the remaining 143us of non-k_attn kernels):
//  - k_convert emits wq/wk/wv/w1/w2 in frag layout [(ostrip*8+kk)<<9]+lane*8.
//  - k_transpose writes xT frag-major (coalesced ushort8 stores from LDS).
//  - k_proj reads xT + weights as base+lane*8 1KB bursts (was 16-scattered-
//    line gathers at 512B stride, ~6cyc/line TA-serialized); PE via float4.
//  - k_attn epilogue writes attT frag-major (stores land in one 512B window).
//  - k_mlp reads attT/w1/w2 as bursts (was 64 gathers/wave).
// Arithmetic identical to R22 -> bit-identical output (absmax 0.0156).
// k_attn body = R22 (stagger + dbuf + V-hoist + cvt_pk + setprio + rs-fold).
// ---------------------------------------------------------------------------

typedef unsigned short u16;
typedef __attribute__((ext_vector_type(8))) unsigned short ushort8;
typedef __attribute__((ext_vector_type(2))) unsigned int uint2v;
typedef __attribute__((ext_vector_type(8))) __bf16 bf16x8;
typedef __attribute__((ext_vector_type(4))) float f32x4;

#define MFMA16(a, b, c) __builtin_amdgcn_mfma_f32_16x16x32_bf16((a), (b), (c), 0, 0, 0)

__device__ __forceinline__ u16 f2bf(float f) {
  unsigned int u = __builtin_bit_cast(unsigned int, f);
  u += 0x7FFFu + ((u >> 16) & 1u);  // round-to-nearest-even
  return (u16)(u >> 16);
}

__device__ __forceinline__ float bf2f(u16 v) {
  return __builtin_bit_cast(float, (unsigned int)v << 16);
}

__device__ __forceinline__ unsigned int cvtpk(float lo, float hi) {
  unsigned int r;
  asm("v_cvt_pk_bf16_f32 %0, %1, %2" : "=v"(r) : "v"(lo), "v"(hi));
  return r;
}

__device__ __forceinline__ bf16x8 ld8(const u16* p) {
  return __builtin_bit_cast(bf16x8, *reinterpret_cast<const ushort8*>(p));
}

__device__ __forceinline__ f32x4 fz4() {
  f32x4 z = {0.f, 0.f, 0.f, 0.f};
  return z;
}

// Fragment-major addressing (u16 units):
//  frag block fb = strip*NK + kchunk; addr = (fb<<9) + lane*8 + e
//  lane = idx15 + 16*g holds tensor[idx = strip*16 + idx15][k = kchunk*32 + g*8 + e]
//  Qf/Kf per batch: 256 istrips x 2 dchunks   (NK=2)
//  xTf/attTf per batch: 256 nstrips x 8 kchunks (NK=8)
//  Vf per batch: 16 cstrips x 128 jchunks     (NK=128)
//  weights: O/16 ostrips x 8 kchunks          (NK=8)

// ---- convert weights fp32 -> bf16 FRAG-MAJOR (one launch, grid 112) -------
__global__ __launch_bounds__(256) void k_convert(
    const float* __restrict__ wq, const float* __restrict__ wk,
    const float* __restrict__ wv, const float* __restrict__ w1,
    const float* __restrict__ w2, u16* __restrict__ dq, u16* __restrict__ dk,
    u16* __restrict__ dv, u16* __restrict__ d1, u16* __restrict__ d2) {
  int t = blockIdx.x * 256 + threadIdx.x;
  int lane = t & 63, fb = t >> 6;  // 448 frag blocks total
  const float* src;
  u16* dst;
  int base;
  if (fb < 32)       { src = wq; dst = dq; base = 0; }
  else if (fb < 64)  { src = wk; dst = dk; base = 32; }
  else if (fb < 192) { src = wv; dst = dv; base = 64; }
  else if (fb < 320) { src = w1; dst = d1; base = 192; }
  else               { src = w2; dst = d2; base = 320; }
  int lfb = fb - base;
  int ostrip = lfb >> 3, kk = lfb & 7;
  int l15 = lane & 15, g = lane >> 4;
  const float* s = src + (ostrip * 16 + l15) * 256 + kk * 32 + g * 8;
  f32x4 a0 = *reinterpret_cast<const f32x4*>(s);
  f32x4 a1 = *reinterpret_cast<const f32x4*>(s + 4);
  ushort8 v;
#pragma unroll
  for (int e = 0; e < 4; ++e) { v[e] = f2bf(a0[e]); v[4 + e] = f2bf(a1[e]); }
  *reinterpret_cast<ushort8*>(dst + ((size_t)lfb << 9) + lane * 8) = v;
}

// ---- x [b][256][4096] fp32 -> xTf frag-major bf16 (LDS-tiled) -------------
__global__ __launch_bounds__(256) void k_transpose(const float* __restrict__ x,
                                                   u16* __restrict__ xT) {
  __shared__ float t[64][65];
  int n0 = blockIdx.x * 64, c0 = blockIdx.y * 64, b = blockIdx.z;
  int tx = threadIdx.x & 63, ty = threadIdx.x >> 6;
  const float* xb = x + ((size_t)b * 256 + c0) * 4096 + n0;
#pragma unroll
  for (int i = 0; i < 64; i += 4) t[ty + i][tx] = xb[(size_t)(ty + i) * 4096 + tx];
  __syncthreads();
  // frag write: wave w owns nstrip (n0>>4)+w; q picks kchunk (c0>>5)+q
  int lane = tx, w = ty;
  int l15 = lane & 15, g = lane >> 4;
  u16* xob = xT + (size_t)b * 1048576;
  int nstrip = (n0 >> 4) + w;
#pragma unroll
  for (int q = 0; q < 2; ++q) {
    int kk = (c0 >> 5) + q;
    int cl = q * 32 + g * 8;
    ushort8 v;
#pragma unroll
    for (int e = 0; e < 8; ++e) v[e] = f2bf(t[cl + e][w * 16 + l15]);
    *reinterpret_cast<ushort8*>(xob + ((size_t)(nstrip * 8 + kk) << 9) + lane * 8) = v;
  }
}

// ---- fused QKV projection: 32-pos tiles, grid 512 linear (b = id&3) -------
// All inputs frag-major (1KB bursts); Q/K/V outputs frag-major (unchanged).
__global__ __launch_bounds__(256) void k_proj(
    const u16* __restrict__ xT, const u16* __restrict__ wq,
    const u16* __restrict__ wk, const u16* __restrict__ wv,
    const float* __restrict__ bQ, const float* __restrict__ bK,
    const float* __restrict__ bV, const float* __restrict__ PE,
    u16* __restrict__ Qt, u16* __restrict__ Kt, u16* __restrict__ Vc) {
  int b = blockIdx.x & 3, n0 = (blockIdx.x >> 2) * 32;
  int lane = threadIdx.x & 63, wid = threadIdx.x >> 6;
  int l15 = lane & 15, g = lane >> 4;
  const u16* xf = xT + (size_t)b * 1048576;

  f32x4 aq[2], ak[2], av[4][2];
#pragma unroll
  for (int m = 0; m < 2; ++m) { aq[m] = fz4(); ak[m] = fz4(); }
#pragma unroll
  for (int m = 0; m < 4; ++m)
#pragma unroll
    for (int n = 0; n < 2; ++n) av[m][n] = fz4();

  for (int kk = 0; kk < 8; ++kk) {
    bf16x8 xa[2];
#pragma unroll
    for (int m = 0; m < 2; ++m)
      xa[m] = ld8(xf + ((((n0 >> 4) + m) * 8 + kk) << 9) + lane * 8);
    bf16x8 fq = ld8(wq + ((wid * 8 + kk) << 9) + lane * 8);
    bf16x8 fk = ld8(wk + ((wid * 8 + kk) << 9) + lane * 8);
#pragma unroll
    for (int m = 0; m < 2; ++m) {
      aq[m] = MFMA16(xa[m], fq, aq[m]);
      ak[m] = MFMA16(xa[m], fk, ak[m]);
    }
    bf16x8 fv[4];
#pragma unroll
    for (int m = 0; m < 4; ++m)
      fv[m] = ld8(wv + (((4 * wid + m) * 8 + kk) << 9) + lane * 8);
#pragma unroll
    for (int m = 0; m < 4; ++m)
#pragma unroll
      for (int n = 0; n < 2; ++n) av[m][n] = MFMA16(fv[m], xa[n], av[m][n]);
  }

  // Q/K fragment writes: o = 16*wid+l15 (col), pos = n0+16m+4g+r (row)
  int o = 16 * wid + l15;
  int dc = wid >> 1;                      // o>>5
  int gp = (16 * (wid & 1) + l15) >> 3;   // (o&31)>>3
  int eo = l15 & 7;                       // o&7
  u16* qf = Qt + (size_t)b * 262144;
  u16* kf = Kt + (size_t)b * 262144;
#pragma unroll
  for (int m = 0; m < 2; ++m) {
    int istrip = (n0 >> 4) + m;
    f32x4 pe4 = *reinterpret_cast<const f32x4*>(PE + o * 4096 + n0 + 16 * m + 4 * g);
#pragma unroll
    for (int r = 0; r < 4; ++r) {
      size_t a = (size_t)(((istrip * 2 + dc) << 9) + ((4 * g + r) + 16 * gp) * 8 + eo);
      qf[a] = f2bf(aq[m][r] + bQ[o] + pe4[r]);
      kf[a] = f2bf(ak[m][r] + bK[o] + pe4[r]);
    }
  }
  // V fragment writes: c = 64wid+16m+4g+r (row idx), pos = n0+16n+l15 (col k)
  u16* vf = Vc + (size_t)b * 1048576;
  int jchunk = n0 >> 5;
#pragma unroll
  for (int m = 0; m < 4; ++m) {
    int cstrip = 4 * wid + m;
#pragma unroll
    for (int r = 0; r < 4; ++r) {
      int c15 = 4 * g + r;
      float bvv = bV[64 * wid + 16 * m + c15];
#pragma unroll
      for (int n = 0; n < 2; ++n) {
        size_t a = (size_t)(((cstrip * 128 + jchunk) << 9) +
                            (c15 + 16 * (2 * n + (l15 >> 3))) * 8 + (l15 & 7));
        vf[a] = f2bf(av[m][n][r] + bvv);
      }
    }
  }
}

// ---- pass 1: column sums + fold 1/colsum into Vf, 512 thr, grid 256 -------
__global__ __launch_bounds__(512) void k_colsum(const u16* __restrict__ Qt,
                                                const u16* __restrict__ Kt,
                                                u16* __restrict__ Vc) {
  __shared__ float ps[8][16];
  __shared__ float rsf[64];
  int b = blockIdx.x & 3, j0 = (blockIdx.x >> 2) * 64;
  int lane = threadIdx.x & 63, wid = threadIdx.x >> 6;  // wid in [0,8)
  int l15 = lane & 15, g = lane >> 4;
  int w4 = wid & 3, ihalf = wid >> 2;
  const u16* qf = Qt + (size_t)b * 262144;
  const u16* kf = Kt + (size_t)b * 262144;
  int jstrip = (j0 >> 4) + w4;
  bf16x8 fk[2];
#pragma unroll
  for (int h = 0; h < 2; ++h)
    fk[h] = ld8(kf + ((jstrip * 2 + h) << 9) + lane * 8);
  float part = 0.f;
  for (int i0 = ihalf * 2048; i0 < ihalf * 2048 + 2048; i0 += 64) {
    f32x4 acc[4];
#pragma unroll
    for (int m = 0; m < 4; ++m) acc[m] = fz4();
#pragma unroll
    for (int m = 0; m < 4; ++m) {
      int ib = ((i0 >> 4) + m) * 2;
      acc[m] = MFMA16(ld8(qf + (ib << 9) + lane * 8), fk[0], acc[m]);
      acc[m] = MFMA16(ld8(qf + ((ib + 1) << 9) + lane * 8), fk[1], acc[m]);
    }
#pragma unroll
    for (int m = 0; m < 4; ++m)
#pragma unroll
      for (int r = 0; r < 4; ++r) part += __expf(acc[m][r] * 0.125f);
  }
  part += __shfl_xor(part, 16);
  part += __shfl_xor(part, 32);
  if (g == 0) ps[wid][l15] = part;
  __syncthreads();
  if (threadIdx.x < 64) {
    int jj = threadIdx.x;
    rsf[jj] = 1.0f / (ps[jj >> 4][jj & 15] + ps[(jj >> 4) + 4][jj & 15]);
  }
  __syncthreads();
  // scale Vf for j in [j0, j0+64), all 256 channels (2 threads / channel)
  {
    int c = threadIdx.x >> 1, half = threadIdx.x & 1;
    int cstrip = c >> 4, c15 = c & 15;
    u16* vb2 = Vc + (size_t)b * 1048576;
#pragma unroll
    for (int q = 0; q < 2; ++q) {
      int jo = half * 32 + q * 16;
#pragma unroll
      for (int s = 0; s < 2; ++s) {
        int joo = jo + s * 8;
        int jc = (j0 + joo) >> 5;
        int jg = (joo & 31) >> 3;
        u16* p = vb2 + (((size_t)(cstrip * 128 + jc)) << 9) + (c15 + 16 * jg) * 8;
        ushort8 v = *reinterpret_cast<const ushort8*>(p);
        ushort8 ov;
#pragma unroll
        for (int e = 0; e < 8; ++e) ov[e] = f2bf(bf2f(v[e]) * rsf[joo + e]);
        *reinterpret_cast<ushort8*>(p) = ov;
      }
    }
  }
}

// ---- pass 2: attention, 1024 thr, grid 256 linear (b = id&3, XCD-pin) -----
// R22 body; epilogue writes attT FRAG-MAJOR for k_mlp's burst reads.
__global__ __launch_bounds__(1024, 4) void k_attn(
    const u16* __restrict__ Qt, const u16* __restrict__ Kt,
    const u16* __restrict__ Vc, u16* __restrict__ attT) {
  __shared__ u16 P[2][64][264];  // dbuf; row 528 B (33x16B)
  int b = blockIdx.x & 3, i0 = (blockIdx.x >> 2) * 64;
  int lane = threadIdx.x & 63, wid = threadIdx.x >> 6;  // wid in [0,16)
  int l15 = lane & 15, g = lane >> 4;
  int ih = wid >> 3, cw = wid & 7;  // PV tile: i-half, 32-c strip
  const u16* qf = Qt + (size_t)b * 262144;
  const u16* kf = Kt + (size_t)b * 262144;
  const u16* vf = Vc + (size_t)b * 1048576;

  bf16x8 aq[4][2];
#pragma unroll
  for (int m = 0; m < 4; ++m)
#pragma unroll
    for (int h = 0; h < 2; ++h)
      aq[m][h] = ld8(qf + ((((i0 >> 4) + m) * 2 + h) << 9) + lane * 8);

  f32x4 oacc[2][2];  // [m][cs]: i = i0+32ih+16m+4g+r, c = 32cw+16cs+l15
#pragma unroll
  for (int m = 0; m < 2; ++m)
#pragma unroll
    for (int cs = 0; cs < 2; ++cs) oacc[m][cs] = fz4();

  const u16* kl = kf + lane * 8;
  bf16x8 fk0 = ld8(kl + ((wid * 2 + 0) << 9));
  bf16x8 fk1 = ld8(kl + ((wid * 2 + 1) << 9));

  auto S_phase = [&](int j0, int sbuf) {
    f32x4 s[4];
#pragma unroll
    for (int m = 0; m < 4; ++m) {
      s[m] = fz4();
      s[m] = MFMA16(fk0, aq[m][0], s[m]);
      s[m] = MFMA16(fk1, aq[m][1], s[m]);
    }
#pragma unroll
    for (int m = 0; m < 4; ++m) {
      float e0 = __expf(s[m][0] * 0.125f);
      float e1 = __expf(s[m][1] * 0.125f);
      float e2 = __expf(s[m][2] * 0.125f);
      float e3 = __expf(s[m][3] * 0.125f);
      uint2v w = {cvtpk(e0, e1), cvtpk(e2, e3)};
      *reinterpret_cast<uint2v*>(&P[sbuf][16 * m + l15][16 * wid + 4 * g]) = w;
    }
    if (j0 < 3840) {
      int jstrip = ((j0 + 256) >> 4) + wid;
      fk0 = ld8(kl + ((jstrip * 2 + 0) << 9));
      fk1 = ld8(kl + ((jstrip * 2 + 1) << 9));
    }
  };
  auto PV_phase = [&](int j0, int pbuf, const bf16x8 (&fvp)[2][4]) {
    __builtin_amdgcn_s_setprio(1);
#pragma unroll
    for (int h = 0; h < 8; ++h) {
      bf16x8 ap[2];
#pragma unroll
      for (int m = 0; m < 2; ++m)
        ap[m] = ld8(&P[pbuf][32 * ih + 16 * m + l15][h * 32 + 8 * g]);
      bf16x8 f0, f1;
      if (h < 4) {
        f0 = fvp[0][h];
        f1 = fvp[1][h];
      } else {
        f0 = ld8(vf + (((2 * cw + 0) * 128 + (j0 >> 5) + h) << 9) + lane * 8);
        f1 = ld8(vf + (((2 * cw + 1) * 128 + (j0 >> 5) + h) << 9) + lane * 8);
      }
      oacc[0][0] = MFMA16(ap[0], f0, oacc[0][0]);
      oacc[0][1] = MFMA16(ap[0], f1, oacc[0][1]);
      oacc[1][0] = MFMA16(ap[1], f0, oacc[1][0]);
      oacc[1][1] = MFMA16(ap[1], f1, oacc[1][1]);
    }
    __builtin_amdgcn_s_setprio(0);
  };

  S_phase(0, 0);
  int buf = 0;
  for (int t = 0; t < 16; ++t) {
    __syncthreads();
    int j0 = t * 256;
    bf16x8 fvp[2][4];
#pragma unroll
    for (int cs = 0; cs < 2; ++cs)
#pragma unroll
      for (int h = 0; h < 4; ++h)
        fvp[cs][h] = ld8(vf + (((2 * cw + cs) * 128 + (j0 >> 5) + h) << 9) + lane * 8);
    if (wid & 1) {
      if (t < 15) S_phase(j0 + 256, buf ^ 1);
      PV_phase(j0, buf, fvp);
    } else {
      PV_phase(j0, buf, fvp);
      if (t < 15) S_phase(j0 + 256, buf ^ 1);
    }
    buf ^= 1;
  }

  // epilogue: attT frag-major. pos = i0+32ih+16m+4g+r -> nstrip, n15 = 4g+r;
  // c = 32cw+16cs+l15 -> kchunk = cw, cg = 2cs+(l15>>3), e = l15&7.
  u16* af = attT + (size_t)b * 1048576;
#pragma unroll
  for (int m = 0; m < 2; ++m) {
    int nstrip = (i0 >> 4) + 2 * ih + m;
#pragma unroll
    for (int cs = 0; cs < 2; ++cs) {
      int cg = 2 * cs + (l15 >> 3);
      int e = l15 & 7;
      u16* basep = af + ((size_t)(nstrip * 8 + cw) << 9) + 16 * cg * 8 + e;
#pragma unroll
      for (int r = 0; r < 4; ++r)
        basep[(4 * g + r) * 8] = f2bf(oacc[m][cs][r]);
    }
  }
}

// ---- fused MLP, 512 thr, grid 256 linear (b = id&3) -----------------------
// attT + w1/w2 read as frag bursts; LDS + epilogue unchanged.
__global__ __launch_bounds__(512) void k_mlp(
    const u16* __restrict__ attT, const u16* __restrict__ w1,
    const float* __restrict__ b1, const u16* __restrict__ w2,
    const float* __restrict__ b2, const float* __restrict__ x,
    float* __restrict__ out) {
  __shared__ u16 hdnS[64][264];
  int b = blockIdx.x & 3, n0 = (blockIdx.x >> 2) * 64;
  int lane = threadIdx.x & 63, wid = threadIdx.x >> 6;  // wid in [0,8)
  int l15 = lane & 15, g = lane >> 4;
  const u16* af = attT + (size_t)b * 1048576;

  // stage 1: hdn = mish(att @ W1^T + b1) -> LDS; wave strip = 32 h-channels
  {
    f32x4 acc[4][2];
#pragma unroll
    for (int m = 0; m < 4; ++m)
#pragma unroll
      for (int n = 0; n < 2; ++n) acc[m][n] = fz4();
    for (int kk = 0; kk < 8; ++kk) {
      bf16x8 am[4], bn[2];
#pragma unroll
      for (int m = 0; m < 4; ++m)
        am[m] = ld8(af + ((((n0 >> 4) + m) * 8 + kk) << 9) + lane * 8);
#pragma unroll
      for (int n = 0; n < 2; ++n)
        bn[n] = ld8(w1 + (((2 * wid + n) * 8 + kk) << 9) + lane * 8);
#pragma unroll
      for (int m = 0; m < 4; ++m)
#pragma unroll
        for (int n = 0; n < 2; ++n) acc[m][n] = MFMA16(am[m], bn[n], acc[m][n]);
    }
#pragma unroll
    for (int m = 0; m < 4; ++m)
#pragma unroll
      for (int n = 0; n < 2; ++n) {
        int hh = 32 * wid + 16 * n + l15;
        float bb = b1[hh];
#pragma unroll
        for (int r = 0; r < 4; ++r) {
          float v = acc[m][n][r] + bb;
          float sp = (v > 15.f) ? v : __logf(1.f + __expf(v));
          float e2 = __expf(-2.f * sp);
          float th = (1.f - e2) / (1.f + e2);
          hdnS[16 * m + 4 * g + r][hh] = f2bf(v * th);
        }
      }
  }
  __syncthreads();

  // stage 2: out = hdn @ W2^T + b2 + x; wave strip = 32 o-channels
  {
    f32x4 acc[2][4];
#pragma unroll
    for (int m = 0; m < 2; ++m)
#pragma unroll
      for (int n = 0; n < 4; ++n) acc[m][n] = fz4();
    for (int kk = 0; kk < 8; ++kk) {
      int ko = kk * 32 + 8 * g;
      bf16x8 am[2], bn[4];
#pragma unroll
      for (int m = 0; m < 2; ++m)
        am[m] = ld8(w2 + (((2 * wid + m) * 8 + kk) << 9) + lane * 8);
#pragma unroll
      for (int n = 0; n < 4; ++n) bn[n] = ld8(&hdnS[16 * n + l15][ko]);
#pragma unroll
      for (int m = 0; m < 2; ++m)
#pragma unroll
        for (int n = 0; n < 4; ++n) acc[m][n] = MFMA16(am[m], bn[n], acc[m][n]);
    }
#pragma unroll
    for (int m = 0; m < 2; ++m)
#pragma unroll
      for (int r = 0; r < 4; ++r) {
        int o = 32 * wid + 16 * m + 4 * g + r;
        float bias = b2[o];
#pragma unroll
        for (int n = 0; n < 4; ++n) {
          int pos = n0 + 16 * n + l15;
          size_t idx = ((size_t)b * 256 + o) * 4096 + pos;
          out[idx] = acc[m][n][r] + bias + x[idx];
        }
      }
  }
}

// ---- workspace layout (bytes) ---------------------------------------------
// attT aliases xT (xT dead after k_proj; attT written by k_attn, read k_mlp).
#define WS_XT 0u          //  8,388,608  xTf  [4][256*8][64][8] bf16 (= attTf)
#define WS_ATT 0u         //  8,388,608  attTf[4][256*8][64][8] bf16 (= xTf)
#define WS_QT 8388608u    //  2,097,152  Qf  [4][256*2][64][8] bf16
#define WS_KT 10485760u   //  2,097,152  Kf  [4][256*2][64][8] bf16
#define WS_VC 12582912u   //  8,388,608  Vf  [4][16*128][64][8] bf16
#define WS_RS 20971520u   //     65,536  (unused)
#define WS_WQ 21037056u   //     32,768  wqf [4*8][64][8]
#define WS_WK 21069824u   //     32,768
#define WS_WV 21102592u   //    131,072  wvf [16*8][64][8]
#define WS_W1 21233664u   //    131,072
#define WS_W2 21364736u   //    131,072   (end: 21,495,808 < 29,884,416)

extern "C" void kernel_launch(void* const* d_in, const int* in_sizes, int n_in,
                              void* d_out, int out_size, void* d_ws, size_t ws_size,
                              hipStream_t stream) {
  (void)in_sizes; (void)n_in; (void)out_size; (void)ws_size;
  const float* x  = (const float*)d_in[0];
  const float* WQ = (const float*)d_in[1];
  const float* bQ = (const float*)d_in[2];
  const float* WK = (const float*)d_in[3];
  const float* bK = (const float*)d_in[4];
  const float* WV = (const float*)d_in[5];
  const float* bV = (const float*)d_in[6];
  const float* PE = (const float*)d_in[7];
  const float* W1 = (const float*)d_in[8];
  const float* b1 = (const float*)d_in[9];
  const float* W2 = (const float*)d_in[10];
  const float* b2 = (const float*)d_in[11];
  float* out = (float*)d_out;
  char* ws = (char*)d_ws;

  u16* xT   = (u16*)(ws + WS_XT);
  u16* Qt   = (u16*)(ws + WS_QT);
  u16* Kt   = (u16*)(ws + WS_KT);
  u16* Vc   = (u16*)(ws + WS_VC);
  u16* attT = (u16*)(ws + WS_ATT);
  u16* wqB  = (u16*)(ws + WS_WQ);
  u16* wkB  = (u16*)(ws + WS_WK);
  u16* wvB  = (u16*)(ws + WS_WV);
  u16* w1B  = (u16*)(ws + WS_W1);
  u16* w2B  = (u16*)(ws + WS_W2);

  k_convert<<<112, 256, 0, stream>>>(WQ, WK, WV, W1, W2, wqB, wkB, wvB, w1B, w2B);
  k_transpose<<<dim3(64, 4, 4), 256, 0, stream>>>(x, xT);
  k_proj<<<512, 256, 0, stream>>>(xT, wqB, wkB, wvB, bQ, bK, bV, PE, Qt, Kt, Vc);
  k_colsum<<<256, 512, 0, stream>>>(Qt, Kt, Vc);
  k_attn<<<256, 1024, 0, stream>>>(Qt, Kt, Vc, attT);
  k_mlp<<<256, 512, 0, stream>>>(attT, w1B, b1, w2B, b2, x, out);
}

// Round 12
// 196.756 us; speedup vs baseline: 1.1201x; 1.0686x over previous
//
#include <hip/hip_runtime.h>

// ---------------------------------------------------------------------------
// AttentionHead: B=4, C=256, N=4096, QK=64. Column-softmax attention.
// R24 = R23 + FUSION (k_attn block already owns the complete 64rowx256ch
// output tile that k_mlp consumes):
//  - k_mlp fused into k_attn epilogue: oacc -> LDS (P dbuf is dead after the
//    j-loop; att tile in P[0], hdn tile in P[1]), then 2 MFMA stages with 16
//    waves (wave = 16-channel strip, ostrip = wid matches the 16-ostrip w1/w2
//    frag layout). Kills the attT global round-trip (16.8 MB) + 1 launch.
//  - k_convert + k_transpose fused into k_prep (branch on blockIdx).
// Launches 6 -> 4. k_attn j-loop, k_proj, k_colsum byte-identical to R23.
// Arithmetic identical to R22/R23 (absmax 0.0156 expected unchanged).
// ---------------------------------------------------------------------------

typedef unsigned short u16;
typedef __attribute__((ext_vector_type(8))) unsigned short ushort8;
typedef __attribute__((ext_vector_type(2))) unsigned int uint2v;
typedef __attribute__((ext_vector_type(8))) __bf16 bf16x8;
typedef __attribute__((ext_vector_type(4))) float f32x4;

#define MFMA16(a, b, c) __builtin_amdgcn_mfma_f32_16x16x32_bf16((a), (b), (c), 0, 0, 0)

__device__ __forceinline__ u16 f2bf(float f) {
  unsigned int u = __builtin_bit_cast(unsigned int, f);
  u += 0x7FFFu + ((u >> 16) & 1u);  // round-to-nearest-even
  return (u16)(u >> 16);
}

__device__ __forceinline__ float bf2f(u16 v) {
  return __builtin_bit_cast(float, (unsigned int)v << 16);
}

__device__ __forceinline__ unsigned int cvtpk(float lo, float hi) {
  unsigned int r;
  asm("v_cvt_pk_bf16_f32 %0, %1, %2" : "=v"(r) : "v"(lo), "v"(hi));
  return r;
}

__device__ __forceinline__ bf16x8 ld8(const u16* p) {
  return __builtin_bit_cast(bf16x8, *reinterpret_cast<const ushort8*>(p));
}

__device__ __forceinline__ f32x4 fz4() {
  f32x4 z = {0.f, 0.f, 0.f, 0.f};
  return z;
}

// Fragment-major addressing (u16 units):
//  frag block fb = strip*NK + kchunk; addr = (fb<<9) + lane*8 + e
//  lane = idx15 + 16*g holds tensor[idx = strip*16 + idx15][k = kchunk*32 + g*8 + e]
//  Qf/Kf per batch: 256 istrips x 2 dchunks (NK=2); xTf: 256 x 8 (NK=8)
//  Vf per batch: 16 cstrips x 128 jchunks (NK=128); weights: O/16 x 8 (NK=8)

// ---- fused prep: transpose (blocks 0..1023) + weight convert (1024..1135) -
__global__ __launch_bounds__(256) void k_prep(
    const float* __restrict__ x, const float* __restrict__ wq,
    const float* __restrict__ wk, const float* __restrict__ wv,
    const float* __restrict__ w1, const float* __restrict__ w2,
    u16* __restrict__ xT, u16* __restrict__ dq, u16* __restrict__ dk,
    u16* __restrict__ dv, u16* __restrict__ d1, u16* __restrict__ d2) {
  __shared__ float t[64][65];
  int id = blockIdx.x;
  if (id < 1024) {
    int n0 = (id & 63) * 64, c0 = ((id >> 6) & 3) * 64, b = id >> 8;
    int tx = threadIdx.x & 63, ty = threadIdx.x >> 6;
    const float* xb = x + ((size_t)b * 256 + c0) * 4096 + n0;
#pragma unroll
    for (int i = 0; i < 64; i += 4) t[ty + i][tx] = xb[(size_t)(ty + i) * 4096 + tx];
    __syncthreads();
    int lane = tx, w = ty;
    int l15 = lane & 15, g = lane >> 4;
    u16* xob = xT + (size_t)b * 1048576;
    int nstrip = (n0 >> 4) + w;
#pragma unroll
    for (int q = 0; q < 2; ++q) {
      int kk = (c0 >> 5) + q;
      int cl = q * 32 + g * 8;
      ushort8 v;
#pragma unroll
      for (int e = 0; e < 8; ++e) v[e] = f2bf(t[cl + e][w * 16 + l15]);
      *reinterpret_cast<ushort8*>(xob + ((size_t)(nstrip * 8 + kk) << 9) + lane * 8) = v;
    }
  } else {
    int tt = (id - 1024) * 256 + threadIdx.x;
    int lane = tt & 63, fb = tt >> 6;  // 448 frag blocks total
    const float* src;
    u16* dst;
    int base;
    if (fb < 32)       { src = wq; dst = dq; base = 0; }
    else if (fb < 64)  { src = wk; dst = dk; base = 32; }
    else if (fb < 192) { src = wv; dst = dv; base = 64; }
    else if (fb < 320) { src = w1; dst = d1; base = 192; }
    else               { src = w2; dst = d2; base = 320; }
    int lfb = fb - base;
    int ostrip = lfb >> 3, kk = lfb & 7;
    int l15 = lane & 15, g = lane >> 4;
    const float* s = src + (ostrip * 16 + l15) * 256 + kk * 32 + g * 8;
    f32x4 a0 = *reinterpret_cast<const f32x4*>(s);
    f32x4 a1 = *reinterpret_cast<const f32x4*>(s + 4);
    ushort8 v;
#pragma unroll
    for (int e = 0; e < 4; ++e) { v[e] = f2bf(a0[e]); v[4 + e] = f2bf(a1[e]); }
    *reinterpret_cast<ushort8*>(dst + ((size_t)lfb << 9) + lane * 8) = v;
  }
}

// ---- fused QKV projection: 32-pos tiles, grid 512 linear (b = id&3) -------
__global__ __launch_bounds__(256) void k_proj(
    const u16* __restrict__ xT, const u16* __restrict__ wq,
    const u16* __restrict__ wk, const u16* __restrict__ wv,
    const float* __restrict__ bQ, const float* __restrict__ bK,
    const float* __restrict__ bV, const float* __restrict__ PE,
    u16* __restrict__ Qt, u16* __restrict__ Kt, u16* __restrict__ Vc) {
  int b = blockIdx.x & 3, n0 = (blockIdx.x >> 2) * 32;
  int lane = threadIdx.x & 63, wid = threadIdx.x >> 6;
  int l15 = lane & 15, g = lane >> 4;
  const u16* xf = xT + (size_t)b * 1048576;

  f32x4 aq[2], ak[2], av[4][2];
#pragma unroll
  for (int m = 0; m < 2; ++m) { aq[m] = fz4(); ak[m] = fz4(); }
#pragma unroll
  for (int m = 0; m < 4; ++m)
#pragma unroll
    for (int n = 0; n < 2; ++n) av[m][n] = fz4();

  for (int kk = 0; kk < 8; ++kk) {
    bf16x8 xa[2];
#pragma unroll
    for (int m = 0; m < 2; ++m)
      xa[m] = ld8(xf + ((((n0 >> 4) + m) * 8 + kk) << 9) + lane * 8);
    bf16x8 fq = ld8(wq + ((wid * 8 + kk) << 9) + lane * 8);
    bf16x8 fk = ld8(wk + ((wid * 8 + kk) << 9) + lane * 8);
#pragma unroll
    for (int m = 0; m < 2; ++m) {
      aq[m] = MFMA16(xa[m], fq, aq[m]);
      ak[m] = MFMA16(xa[m], fk, ak[m]);
    }
    bf16x8 fv[4];
#pragma unroll
    for (int m = 0; m < 4; ++m)
      fv[m] = ld8(wv + (((4 * wid + m) * 8 + kk) << 9) + lane * 8);
#pragma unroll
    for (int m = 0; m < 4; ++m)
#pragma unroll
      for (int n = 0; n < 2; ++n) av[m][n] = MFMA16(fv[m], xa[n], av[m][n]);
  }

  int o = 16 * wid + l15;
  int dc = wid >> 1;
  int gp = (16 * (wid & 1) + l15) >> 3;
  int eo = l15 & 7;
  u16* qf = Qt + (size_t)b * 262144;
  u16* kf = Kt + (size_t)b * 262144;
#pragma unroll
  for (int m = 0; m < 2; ++m) {
    int istrip = (n0 >> 4) + m;
    f32x4 pe4 = *reinterpret_cast<const f32x4*>(PE + o * 4096 + n0 + 16 * m + 4 * g);
#pragma unroll
    for (int r = 0; r < 4; ++r) {
      size_t a = (size_t)(((istrip * 2 + dc) << 9) + ((4 * g + r) + 16 * gp) * 8 + eo);
      qf[a] = f2bf(aq[m][r] + bQ[o] + pe4[r]);
      kf[a] = f2bf(ak[m][r] + bK[o] + pe4[r]);
    }
  }
  u16* vf = Vc + (size_t)b * 1048576;
  int jchunk = n0 >> 5;
#pragma unroll
  for (int m = 0; m < 4; ++m) {
    int cstrip = 4 * wid + m;
#pragma unroll
    for (int r = 0; r < 4; ++r) {
      int c15 = 4 * g + r;
      float bvv = bV[64 * wid + 16 * m + c15];
#pragma unroll
      for (int n = 0; n < 2; ++n) {
        size_t a = (size_t)(((cstrip * 128 + jchunk) << 9) +
                            (c15 + 16 * (2 * n + (l15 >> 3))) * 8 + (l15 & 7));
        vf[a] = f2bf(av[m][n][r] + bvv);
      }
    }
  }
}

// ---- pass 1: column sums + fold 1/colsum into Vf, 512 thr, grid 256 -------
__global__ __launch_bounds__(512) void k_colsum(const u16* __restrict__ Qt,
                                                const u16* __restrict__ Kt,
                                                u16* __restrict__ Vc) {
  __shared__ float ps[8][16];
  __shared__ float rsf[64];
  int b = blockIdx.x & 3, j0 = (blockIdx.x >> 2) * 64;
  int lane = threadIdx.x & 63, wid = threadIdx.x >> 6;  // wid in [0,8)
  int l15 = lane & 15, g = lane >> 4;
  int w4 = wid & 3, ihalf = wid >> 2;
  const u16* qf = Qt + (size_t)b * 262144;
  const u16* kf = Kt + (size_t)b * 262144;
  int jstrip = (j0 >> 4) + w4;
  bf16x8 fk[2];
#pragma unroll
  for (int h = 0; h < 2; ++h)
    fk[h] = ld8(kf + ((jstrip * 2 + h) << 9) + lane * 8);
  float part = 0.f;
  for (int i0 = ihalf * 2048; i0 < ihalf * 2048 + 2048; i0 += 64) {
    f32x4 acc[4];
#pragma unroll
    for (int m = 0; m < 4; ++m) acc[m] = fz4();
#pragma unroll
    for (int m = 0; m < 4; ++m) {
      int ib = ((i0 >> 4) + m) * 2;
      acc[m] = MFMA16(ld8(qf + (ib << 9) + lane * 8), fk[0], acc[m]);
      acc[m] = MFMA16(ld8(qf + ((ib + 1) << 9) + lane * 8), fk[1], acc[m]);
    }
#pragma unroll
    for (int m = 0; m < 4; ++m)
#pragma unroll
      for (int r = 0; r < 4; ++r) part += __expf(acc[m][r] * 0.125f);
  }
  part += __shfl_xor(part, 16);
  part += __shfl_xor(part, 32);
  if (g == 0) ps[wid][l15] = part;
  __syncthreads();
  if (threadIdx.x < 64) {
    int jj = threadIdx.x;
    rsf[jj] = 1.0f / (ps[jj >> 4][jj & 15] + ps[(jj >> 4) + 4][jj & 15]);
  }
  __syncthreads();
  {
    int c = threadIdx.x >> 1, half = threadIdx.x & 1;
    int cstrip = c >> 4, c15 = c & 15;
    u16* vb2 = Vc + (size_t)b * 1048576;
#pragma unroll
    for (int q = 0; q < 2; ++q) {
      int jo = half * 32 + q * 16;
#pragma unroll
      for (int s = 0; s < 2; ++s) {
        int joo = jo + s * 8;
        int jc = (j0 + joo) >> 5;
        int jg = (joo & 31) >> 3;
        u16* p = vb2 + (((size_t)(cstrip * 128 + jc)) << 9) + (c15 + 16 * jg) * 8;
        ushort8 v = *reinterpret_cast<const ushort8*>(p);
        ushort8 ov;
#pragma unroll
        for (int e = 0; e < 8; ++e) ov[e] = f2bf(bf2f(v[e]) * rsf[joo + e]);
        *reinterpret_cast<ushort8*>(p) = ov;
      }
    }
  }
}

// ---- pass 2: attention + fused MLP, 1024 thr, grid 256 (b = id&3) ---------
// j-loop = R22/R23 (stagger + dbuf + V-hoist + cvt_pk + setprio + rs-fold).
// Then MLP block-locally: oacc -> LDS (P[0] = att tile, P[1] = hdn tile),
// stage1 mish(att@W1^T+b1), stage2 hdn@W2^T+b2+x -> out. 16 waves, wave =
// 16-channel strip (ostrip = wid matches w1/w2 frag layout).
__global__ __launch_bounds__(1024, 4) void k_attn(
    const u16* __restrict__ Qt, const u16* __restrict__ Kt,
    const u16* __restrict__ Vc, const u16* __restrict__ w1,
    const float* __restrict__ b1, const u16* __restrict__ w2,
    const float* __restrict__ b2, const float* __restrict__ x,
    float* __restrict__ out) {
  __shared__ u16 P[2][64][264];  // dbuf; reused as att/hdn tiles for MLP
  int b = blockIdx.x & 3, i0 = (blockIdx.x >> 2) * 64;
  int lane = threadIdx.x & 63, wid = threadIdx.x >> 6;  // wid in [0,16)
  int l15 = lane & 15, g = lane >> 4;
  int ih = wid >> 3, cw = wid & 7;  // PV tile: i-half, 32-c strip
  const u16* qf = Qt + (size_t)b * 262144;
  const u16* kf = Kt + (size_t)b * 262144;
  const u16* vf = Vc + (size_t)b * 1048576;

  bf16x8 aq[4][2];
#pragma unroll
  for (int m = 0; m < 4; ++m)
#pragma unroll
    for (int h = 0; h < 2; ++h)
      aq[m][h] = ld8(qf + ((((i0 >> 4) + m) * 2 + h) << 9) + lane * 8);

  f32x4 oacc[2][2];  // [m][cs]: i = i0+32ih+16m+4g+r, c = 32cw+16cs+l15
#pragma unroll
  for (int m = 0; m < 2; ++m)
#pragma unroll
    for (int cs = 0; cs < 2; ++cs) oacc[m][cs] = fz4();

  const u16* kl = kf + lane * 8;
  bf16x8 fk0 = ld8(kl + ((wid * 2 + 0) << 9));
  bf16x8 fk1 = ld8(kl + ((wid * 2 + 1) << 9));

  auto S_phase = [&](int j0, int sbuf) {
    f32x4 s[4];
#pragma unroll
    for (int m = 0; m < 4; ++m) {
      s[m] = fz4();
      s[m] = MFMA16(fk0, aq[m][0], s[m]);
      s[m] = MFMA16(fk1, aq[m][1], s[m]);
    }
#pragma unroll
    for (int m = 0; m < 4; ++m) {
      float e0 = __expf(s[m][0] * 0.125f);
      float e1 = __expf(s[m][1] * 0.125f);
      float e2 = __expf(s[m][2] * 0.125f);
      float e3 = __expf(s[m][3] * 0.125f);
      uint2v w = {cvtpk(e0, e1), cvtpk(e2, e3)};
      *reinterpret_cast<uint2v*>(&P[sbuf][16 * m + l15][16 * wid + 4 * g]) = w;
    }
    if (j0 < 3840) {
      int jstrip = ((j0 + 256) >> 4) + wid;
      fk0 = ld8(kl + ((jstrip * 2 + 0) << 9));
      fk1 = ld8(kl + ((jstrip * 2 + 1) << 9));
    }
  };
  auto PV_phase = [&](int j0, int pbuf, const bf16x8 (&fvp)[2][4]) {
    __builtin_amdgcn_s_setprio(1);
#pragma unroll
    for (int h = 0; h < 8; ++h) {
      bf16x8 ap[2];
#pragma unroll
      for (int m = 0; m < 2; ++m)
        ap[m] = ld8(&P[pbuf][32 * ih + 16 * m + l15][h * 32 + 8 * g]);
      bf16x8 f0, f1;
      if (h < 4) {
        f0 = fvp[0][h];
        f1 = fvp[1][h];
      } else {
        f0 = ld8(vf + (((2 * cw + 0) * 128 + (j0 >> 5) + h) << 9) + lane * 8);
        f1 = ld8(vf + (((2 * cw + 1) * 128 + (j0 >> 5) + h) << 9) + lane * 8);
      }
      oacc[0][0] = MFMA16(ap[0], f0, oacc[0][0]);
      oacc[0][1] = MFMA16(ap[0], f1, oacc[0][1]);
      oacc[1][0] = MFMA16(ap[1], f0, oacc[1][0]);
      oacc[1][1] = MFMA16(ap[1], f1, oacc[1][1]);
    }
    __builtin_amdgcn_s_setprio(0);
  };

  S_phase(0, 0);
  int buf = 0;
  for (int t = 0; t < 16; ++t) {
    __syncthreads();
    int j0 = t * 256;
    bf16x8 fvp[2][4];
#pragma unroll
    for (int cs = 0; cs < 2; ++cs)
#pragma unroll
      for (int h = 0; h < 4; ++h)
        fvp[cs][h] = ld8(vf + (((2 * cw + cs) * 128 + (j0 >> 5) + h) << 9) + lane * 8);
    if (wid & 1) {
      if (t < 15) S_phase(j0 + 256, buf ^ 1);
      PV_phase(j0, buf, fvp);
    } else {
      PV_phase(j0, buf, fvp);
      if (t < 15) S_phase(j0 + 256, buf ^ 1);
    }
    buf ^= 1;
  }

  // ---- fused MLP on the block's 64x256 tile ----
  u16 (*attL)[264] = P[0];  // att tile (P dead after j-loop)
  u16 (*hdnL)[264] = P[1];  // hdn tile
  __syncthreads();  // all PV reads of P complete
#pragma unroll
  for (int m = 0; m < 2; ++m)
#pragma unroll
    for (int cs = 0; cs < 2; ++cs)
#pragma unroll
      for (int r = 0; r < 4; ++r)
        attL[32 * ih + 16 * m + 4 * g + r][32 * cw + 16 * cs + l15] =
            f2bf(oacc[m][cs][r]);
  __syncthreads();

  // stage 1: hdn = mish(att @ W1^T + b1); wave strip = 16 h (ostrip = wid)
  {
    f32x4 acc1[4];
#pragma unroll
    for (int m = 0; m < 4; ++m) acc1[m] = fz4();
    for (int kk = 0; kk < 8; ++kk) {
      bf16x8 bn = ld8(w1 + ((wid * 8 + kk) << 9) + lane * 8);
#pragma unroll
      for (int m = 0; m < 4; ++m) {
        bf16x8 am = ld8(&attL[16 * m + l15][kk * 32 + 8 * g]);
        acc1[m] = MFMA16(am, bn, acc1[m]);
      }
    }
    float bb = b1[16 * wid + l15];
#pragma unroll
    for (int m = 0; m < 4; ++m)
#pragma unroll
      for (int r = 0; r < 4; ++r) {
        float v = acc1[m][r] + bb;
        float sp = (v > 15.f) ? v : __logf(1.f + __expf(v));
        float e2 = __expf(-2.f * sp);
        float th = (1.f - e2) / (1.f + e2);
        hdnL[16 * m + 4 * g + r][16 * wid + l15] = f2bf(v * th);
      }
  }
  __syncthreads();

  // stage 2: out = hdn @ W2^T + b2 + x; wave strip = 16 o (ostrip = wid)
  {
    f32x4 acc2[4];
#pragma unroll
    for (int n = 0; n < 4; ++n) acc2[n] = fz4();
    for (int kk = 0; kk < 8; ++kk) {
      bf16x8 am = ld8(w2 + ((wid * 8 + kk) << 9) + lane * 8);
#pragma unroll
      for (int n = 0; n < 4; ++n) {
        bf16x8 bn = ld8(&hdnL[16 * n + l15][kk * 32 + 8 * g]);
        acc2[n] = MFMA16(am, bn, acc2[n]);
      }
    }
    f32x4 b2v = *reinterpret_cast<const f32x4*>(b2 + 16 * wid + 4 * g);
#pragma unroll
    for (int r = 0; r < 4; ++r) {
      int o = 16 * wid + 4 * g + r;
#pragma unroll
      for (int n = 0; n < 4; ++n) {
        int pos = i0 + 16 * n + l15;
        size_t idx = ((size_t)b * 256 + o) * 4096 + pos;
        out[idx] = acc2[n][r] + b2v[r] + x[idx];
      }
    }
  }
}

// ---- workspace layout (bytes) ---------------------------------------------
#define WS_XT 0u          //  8,388,608  xTf  [4][256*8][64][8] bf16
#define WS_QT 8388608u    //  2,097,152  Qf  [4][256*2][64][8] bf16
#define WS_KT 10485760u   //  2,097,152  Kf  [4][256*2][64][8] bf16
#define WS_VC 12582912u   //  8,388,608  Vf  [4][16*128][64][8] bf16
#define WS_WQ 21037056u   //     32,768  wqf [4*8][64][8]
#define WS_WK 21069824u   //     32,768
#define WS_WV 21102592u   //    131,072  wvf [16*8][64][8]
#define WS_W1 21233664u   //    131,072
#define WS_W2 21364736u   //    131,072   (end: 21,495,808 < 29,884,416)

extern "C" void kernel_launch(void* const* d_in, const int* in_sizes, int n_in,
                              void* d_out, int out_size, void* d_ws, size_t ws_size,
                              hipStream_t stream) {
  (void)in_sizes; (void)n_in; (void)out_size; (void)ws_size;
  const float* x  = (const float*)d_in[0];
  const float* WQ = (const float*)d_in[1];
  const float* bQ = (const float*)d_in[2];
  const float* WK = (const float*)d_in[3];
  const float* bK = (const float*)d_in[4];
  const float* WV = (const float*)d_in[5];
  const float* bV = (const float*)d_in[6];
  const float* PE = (const float*)d_in[7];
  const float* W1 = (const float*)d_in[8];
  const float* b1 = (const float*)d_in[9];
  const float* W2 = (const float*)d_in[10];
  const float* b2 = (const float*)d_in[11];
  float* out = (float*)d_out;
  char* ws = (char*)d_ws;

  u16* xT   = (u16*)(ws + WS_XT);
  u16* Qt   = (u16*)(ws + WS_QT);
  u16* Kt   = (u16*)(ws + WS_KT);
  u16* Vc   = (u16*)(ws + WS_VC);
  u16* wqB  = (u16*)(ws + WS_WQ);
  u16* wkB  = (u16*)(ws + WS_WK);
  u16* wvB  = (u16*)(ws + WS_WV);
  u16* w1B  = (u16*)(ws + WS_W1);
  u16* w2B  = (u16*)(ws + WS_W2);

  k_prep<<<1136, 256, 0, stream>>>(x, WQ, WK, WV, W1, W2, xT, wqB, wkB, wvB, w1B, w2B);
  k_proj<<<512, 256, 0, stream>>>(xT, wqB, wkB, wvB, bQ, bK, bV, PE, Qt, Kt, Vc);
  k_colsum<<<256, 512, 0, stream>>>(Qt, Kt, Vc);
  k_attn<<<256, 1024, 0, stream>>>(Qt, Kt, Vc, w1B, b1, w2B, b2, x, out);
}